// Round 16
// baseline (389.139 us; speedup 1.0000x reference)
//
#include <hip/hip_runtime.h>
#include <math.h>

#define DMODEL 1024
#define NH 16
#define DHEAD 64
#define DFF 4096
#define BATCH 4
#define SEQ 2048
#define MROWS (BATCH * SEQ)   // 8192
#define LNEPS 1e-5f
#define NT (SEQ / 64)         // 32 kv tiles

typedef __attribute__((ext_vector_type(8))) short bf16x8;
typedef __attribute__((ext_vector_type(4))) float f32x4;
typedef __attribute__((ext_vector_type(16))) float f32x16;
typedef __attribute__((ext_vector_type(4))) unsigned int u32x4;

__device__ inline unsigned short f2bf(float f) {
  unsigned int u = __float_as_uint(f);
  unsigned int r = (u + 0x7fffu + ((u >> 16) & 1u)) >> 16;  // RNE
  return (unsigned short)r;
}
__device__ inline float bf2f(unsigned short b) {
  return __uint_as_float(((unsigned int)b) << 16);
}

__device__ inline void gload16(const unsigned short* g, char* l) {
  __builtin_amdgcn_global_load_lds(
      (const __attribute__((address_space(1))) unsigned int*)g,
      (__attribute__((address_space(3))) unsigned int*)l, 16, 0, 0);
}

__device__ inline float fexp2(float x) {
  float r;
  asm("v_exp_f32 %0, %1" : "=v"(r) : "v"(x));
  return r;
}
__device__ inline unsigned int cvtpk(float lo, float hi) {
  unsigned int r;
  asm("v_cvt_pk_bf16_f32 %0, %1, %2" : "=v"(r) : "v"(lo), "v"(hi));
  return r;
}
__device__ inline void plswap(unsigned int& a, unsigned int& b) {
  asm("v_permlane32_swap_b32 %0, %1" : "+v"(a), "+v"(b));
}

// ---------------------------------------------------------------------------
// Fused prologue: blocks [0,16384) do embedding+pos-enc -> bf16 xb;
// blocks [16384, 28672) do the 4-weight fp32->bf16 conversion.
// ---------------------------------------------------------------------------
__global__ __launch_bounds__(256)
void prep_kernel(const int* __restrict__ tokens, const float* __restrict__ emb,
                 unsigned short* __restrict__ Xb,
                 const float* __restrict__ a, const float* __restrict__ b,
                 const float* __restrict__ c, const float* __restrict__ d,
                 unsigned short* __restrict__ oa, unsigned short* __restrict__ ob,
                 unsigned short* __restrict__ oc, unsigned short* __restrict__ od) {
  const int bid = blockIdx.x;
  if (bid < 16384) {
    const int HALF = DMODEL / 2;
    int idx = bid * 256 + threadIdx.x;
    int row = idx / HALF;
    int j = idx - row * HALF;
    int s = row & (SEQ - 1);
    int tok = tokens[row];
    float2 e = ((const float2*)(emb + (size_t)tok * DMODEL))[j];
    float denom = powf(10000.0f, (2.0f * (float)(2 * j)) / (float)DMODEL);
    float ang = (float)s / denom;
    float sn, cs;
    sincosf(ang, &sn, &cs);
    ushort2 o2;
    o2.x = f2bf(e.x + sn);
    o2.y = f2bf(e.y + cs);
    ((ushort2*)(Xb + (size_t)row * DMODEL))[j] = o2;
  } else {
    int i = (bid - 16384) * 256 + threadIdx.x;
    const float* src; unsigned short* dst; int off;
    if (i < 786432)       { src = a; dst = oa; off = 0; }
    else if (i < 1048576) { src = b; dst = ob; off = 786432; }
    else if (i < 2097152) { src = c; dst = oc; off = 1048576; }
    else                  { src = d; dst = od; off = 2097152; }
    int j = i - off;
    float4 v = ((const float4*)src)[j];
    ushort4 o;
    o.x = f2bf(v.x); o.y = f2bf(v.y); o.z = f2bf(v.z); o.w = f2bf(v.w);
    ((ushort4*)dst)[j] = o;
  }
}

// ---------------------------------------------------------------------------
// gemm8p: 8-phase 256x256 GEMM (round-10 structure; ff1 only).
// ---------------------------------------------------------------------------
__device__ inline void sthalf8(const unsigned short* G, int grow0, int K, int kt,
                               char* smem_, int isB, int half, int t) {
  char* dst = smem_ + ((kt & 1) * 65536) + isB * 32768 + half * 16384;
#pragma unroll
  for (int i = 0; i < 2; ++i) {
    int g = i * 512 + t;
    int r = g >> 3, sl = g & 7;
    int c = sl ^ (r & 7);
    gload16(G + (size_t)(grow0 + half * 128 + r) * K + kt * 64 + c * 8, dst + g * 16);
  }
}

#define VM4_ asm volatile("s_waitcnt vmcnt(4)" ::: "memory")
#define VM2_ asm volatile("s_waitcnt vmcnt(2)" ::: "memory")
#define VM0_ asm volatile("s_waitcnt vmcnt(0)" ::: "memory")

#define PHASE8(bufofs, MG, NP, LA, LB, STAGE_STMT, WAIT_STMT)                   \
  {                                                                             \
    if (LA) {                                                                   \
      _Pragma("unroll") for (int m = 0; m < 4; ++m) {                           \
        int arow = wm * 128 + (MG) * 64 + m * 16 + fr;                          \
        _Pragma("unroll") for (int ks = 0; ks < 2; ++ks)                        \
          af[m][ks] = *(const bf16x8*)(smem + (bufofs) + arow * 128 +           \
                        (((ks * 4 + fq) ^ (arow & 7)) * 16));                   \
      }                                                                         \
    }                                                                           \
    if (LB) {                                                                   \
      _Pragma("unroll") for (int nn = 0; nn < 2; ++nn) {                        \
        int n = (NP) * 2 + nn;                                                  \
        int brow = wn * 64 + n * 16 + fr;                                       \
        _Pragma("unroll") for (int ks = 0; ks < 2; ++ks)                        \
          bf[(NP) * 2 + nn][ks] = *(const bf16x8*)(smem + (bufofs) + 32768 +    \
                        brow * 128 + (((ks * 4 + fq) ^ (brow & 7)) * 16));      \
      }                                                                         \
    }                                                                           \
    STAGE_STMT;                                                                 \
    __builtin_amdgcn_sched_barrier(0);                                          \
    __builtin_amdgcn_s_barrier();                                               \
    asm volatile("s_waitcnt lgkmcnt(0)" ::: "memory");                          \
    __builtin_amdgcn_sched_barrier(0);                                          \
    __builtin_amdgcn_s_setprio(1);                                              \
    _Pragma("unroll") for (int m = 0; m < 4; ++m)                               \
      _Pragma("unroll") for (int nn = 0; nn < 2; ++nn)                          \
        _Pragma("unroll") for (int ks = 0; ks < 2; ++ks)                        \
          acc[(MG) * 4 + m][(NP) * 2 + nn] =                                    \
              __builtin_amdgcn_mfma_f32_16x16x32_bf16(                          \
                  af[m][ks], bf[(NP) * 2 + nn][ks],                             \
                  acc[(MG) * 4 + m][(NP) * 2 + nn], 0, 0, 0);                   \
    __builtin_amdgcn_s_setprio(0);                                              \
    WAIT_STMT;                                                                  \
    __builtin_amdgcn_sched_barrier(0);                                          \
    __builtin_amdgcn_s_barrier();                                               \
    __builtin_amdgcn_sched_barrier(0);                                          \
  }

__global__ __launch_bounds__(512, 2)
void gemm8p(const unsigned short* __restrict__ A, const unsigned short* __restrict__ B,
            const float* __restrict__ bias, const float* __restrict__ resid,
            float* __restrict__ Cf, unsigned short* __restrict__ Cb,
            int M, int N, int K, int relu) {
  extern __shared__ char smem[];   // 131072: 2 bufs x (A 32K + B 32K)

  const int t = threadIdx.x;
  const int lane = t & 63;
  const int wv = t >> 6;
  const int wm = wv >> 2;
  const int wn = wv & 3;
  const int fr = lane & 15;
  const int fq = lane >> 4;

  const int nwg = gridDim.x;
  const int orig = blockIdx.x;
  const int q8 = nwg >> 3;
  const int wgid = (orig & 7) * q8 + (orig >> 3);
  const int stid = wgid >> 2, within = wgid & 3;
  const int sm = within & 1, sn = within >> 1;
  const int Msup = M >> 9;
  const int stm = stid % Msup, stn = stid / Msup;
  const int m0 = (stm * 2 + sm) * 256;
  const int n0 = (stn * 2 + sn) * 256;

  f32x4 acc[8][4];
#pragma unroll
  for (int m = 0; m < 8; ++m)
#pragma unroll
    for (int n = 0; n < 4; ++n) acc[m][n] = (f32x4){0.f, 0.f, 0.f, 0.f};

  const int nk = K / 64;
  const int nj = nk / 2;

  sthalf8(A, m0, K, 0, smem, 0, 0, t);
  sthalf8(A, m0, K, 0, smem, 0, 1, t);
  sthalf8(B, n0, K, 0, smem, 1, 0, t);
  sthalf8(B, n0, K, 0, smem, 1, 1, t);
  sthalf8(B, n0, K, 1, smem, 1, 0, t);
  sthalf8(B, n0, K, 1, smem, 1, 1, t);
  VM4_;
  __builtin_amdgcn_sched_barrier(0);
  __builtin_amdgcn_s_barrier();
  __builtin_amdgcn_sched_barrier(0);

  bf16x8 af[4][2];
  bf16x8 bf[4][2];

  for (int j = 0; j < nj; ++j) {
    const bool st = (j + 1 < nj);
    PHASE8(0, 0, 0, 1, 1, sthalf8(A, m0, K, 2 * j + 1, smem, 0, 0, t), );
    PHASE8(0, 0, 1, 0, 1, sthalf8(A, m0, K, 2 * j + 1, smem, 0, 1, t), );
    PHASE8(0, 1, 1, 1, 0,
           if (st) sthalf8(B, n0, K, 2 * j + 2, smem, 1, 0, t), );
    PHASE8(0, 1, 0, 0, 0,
           if (st) sthalf8(B, n0, K, 2 * j + 2, smem, 1, 1, t),
           { if (st) { VM4_; } else { VM0_; } });
    PHASE8(65536, 0, 0, 1, 1,
           if (st) sthalf8(A, m0, K, 2 * j + 2, smem, 0, 0, t), );
    PHASE8(65536, 0, 1, 0, 1,
           if (st) sthalf8(A, m0, K, 2 * j + 2, smem, 0, 1, t), );
    PHASE8(65536, 1, 1, 1, 0,
           if (st) sthalf8(B, n0, K, 2 * j + 3, smem, 1, 0, t), );
    PHASE8(65536, 1, 0, 0, 0,
           if (st) sthalf8(B, n0, K, 2 * j + 3, smem, 1, 1, t),
           { if (st) { VM4_; } });
  }

  float* slab = (float*)(smem + wv * 4352);
#pragma unroll
  for (int m = 0; m < 8; ++m) {
#pragma unroll
    for (int n = 0; n < 4; ++n)
#pragma unroll
      for (int j = 0; j < 4; ++j)
        slab[(fq * 4 + j) * 68 + n * 16 + fr] = acc[m][n][j];
    int rg0 = m0 + wm * 128 + m * 16;
#pragma unroll
    for (int it = 0; it < 4; ++it) {
      int u = it * 64 + lane;
      int row = u >> 4, seg = u & 15;
      float4 v = *(const float4*)&slab[row * 68 + seg * 4];
      int col = n0 + wn * 64 + seg * 4;
      float4 b4 = *(const float4*)&bias[col];
      v.x += b4.x; v.y += b4.y; v.z += b4.z; v.w += b4.w;
      if (relu) {
        v.x = fmaxf(v.x, 0.f); v.y = fmaxf(v.y, 0.f);
        v.z = fmaxf(v.z, 0.f); v.w = fmaxf(v.w, 0.f);
      }
      size_t idx = (size_t)(rg0 + row) * N + col;
      if (resid) {
        float4 r4 = *(const float4*)&resid[idx];
        v.x += r4.x; v.y += r4.y; v.z += r4.z; v.w += r4.w;
      }
      if (Cf) {
        *(float4*)&Cf[idx] = v;
      } else {
        ushort4 ob;
        ob.x = f2bf(v.x); ob.y = f2bf(v.y); ob.z = f2bf(v.z); ob.w = f2bf(v.w);
        *(ushort4*)&Cb[idx] = ob;
      }
    }
  }
}

// ---------------------------------------------------------------------------
// gemm8p128: fine-phase schedule at BM=256, BN=128 (qkv, out-proj, ff2).
// vtb mode (qkv only): V-region waves write their slab transposed to vtb.
// ---------------------------------------------------------------------------
__device__ inline void stA128(const unsigned short* G, int m0, int K, int kt,
                              int half, char* smem_, int t) {
  char* dst = smem_ + ((kt & 1) * 49152) + half * 16384;
#pragma unroll
  for (int i = 0; i < 2; ++i) {
    int g = i * 512 + t;
    int r = g >> 3, sl = g & 7;
    int c = sl ^ (r & 7);
    gload16(G + (size_t)(m0 + half * 128 + r) * K + kt * 64 + c * 8, dst + g * 16);
  }
}
__device__ inline void stB128(const unsigned short* G, int n0, int K, int kt,
                              char* smem_, int t) {
  char* dst = smem_ + ((kt & 1) * 49152) + 32768;
#pragma unroll
  for (int i = 0; i < 2; ++i) {
    int g = i * 512 + t;
    int r = g >> 3, sl = g & 7;
    int c = sl ^ (r & 7);
    gload16(G + (size_t)(n0 + r) * K + kt * 64 + c * 8, dst + g * 16);
  }
}

#define PH128(bufofs, MG, NP, LA, LB, STAGE_STMT, WAIT_STMT)                    \
  {                                                                             \
    if (LA) {                                                                   \
      _Pragma("unroll") for (int mm = 0; mm < 2; ++mm) {                        \
        int arow = wm * 64 + ((MG) * 2 + mm) * 16 + fr;                         \
        _Pragma("unroll") for (int ks = 0; ks < 2; ++ks)                        \
          af[mm][ks] = *(const bf16x8*)(smem + (bufofs) + arow * 128 +          \
                        (((ks * 4 + fq) ^ (arow & 7)) * 16));                   \
      }                                                                         \
    }                                                                           \
    if (LB) {                                                                   \
      _Pragma("unroll") for (int nn = 0; nn < 2; ++nn) {                        \
        int n = (NP) * 2 + nn;                                                  \
        int brow = wn * 64 + n * 16 + fr;                                       \
        _Pragma("unroll") for (int ks = 0; ks < 2; ++ks)                        \
          bf[(NP) * 2 + nn][ks] = *(const bf16x8*)(smem + (bufofs) + 32768 +    \
                        brow * 128 + (((ks * 4 + fq) ^ (brow & 7)) * 16));      \
      }                                                                         \
    }                                                                           \
    STAGE_STMT;                                                                 \
    __builtin_amdgcn_sched_barrier(0);                                          \
    __builtin_amdgcn_s_barrier();                                               \
    asm volatile("s_waitcnt lgkmcnt(0)" ::: "memory");                          \
    __builtin_amdgcn_sched_barrier(0);                                          \
    __builtin_amdgcn_s_setprio(1);                                              \
    _Pragma("unroll") for (int mm = 0; mm < 2; ++mm)                            \
      _Pragma("unroll") for (int nn = 0; nn < 2; ++nn)                          \
        _Pragma("unroll") for (int ks = 0; ks < 2; ++ks)                        \
          acc[(MG) * 2 + mm][(NP) * 2 + nn] =                                   \
              __builtin_amdgcn_mfma_f32_16x16x32_bf16(                          \
                  af[mm][ks], bf[(NP) * 2 + nn][ks],                            \
                  acc[(MG) * 2 + mm][(NP) * 2 + nn], 0, 0, 0);                  \
    __builtin_amdgcn_s_setprio(0);                                              \
    WAIT_STMT;                                                                  \
    __builtin_amdgcn_sched_barrier(0);                                          \
    __builtin_amdgcn_s_barrier();                                               \
    __builtin_amdgcn_sched_barrier(0);                                          \
  }

__global__ __launch_bounds__(512, 2)
void gemm8p128(const unsigned short* __restrict__ A, const unsigned short* __restrict__ B,
               const float* __restrict__ bias, const float* __restrict__ resid,
               const unsigned short* __restrict__ residb,
               float* __restrict__ Cf, unsigned short* __restrict__ Cb,
               unsigned short* __restrict__ vtb,
               int M, int N, int K, int relu) {
  extern __shared__ char smem[];   // 98304: 2 bufs x (A 32K + B 16K)

  const int t = threadIdx.x;
  const int lane = t & 63;
  const int wv = t >> 6;
  const int wm = wv >> 1;
  const int wn = wv & 1;
  const int fr = lane & 15;
  const int fq = lane >> 4;

  const int nwg = gridDim.x;
  const int orig = blockIdx.x;
  const int q8 = nwg >> 3;
  const int wgid = (orig & 7) * q8 + (orig >> 3);
  const int stid = wgid >> 2, within = wgid & 3;
  const int sm = within & 1, sn = within >> 1;
  const int Msup = M >> 9;
  const int stm = stid % Msup, stn = stid / Msup;
  const int m0 = (stm * 2 + sm) * 256;
  const int n0 = (stn * 2 + sn) * 128;

  f32x4 acc[4][4];
#pragma unroll
  for (int m = 0; m < 4; ++m)
#pragma unroll
    for (int n = 0; n < 4; ++n) acc[m][n] = (f32x4){0.f, 0.f, 0.f, 0.f};

  const int nk = K / 64;
  const int nj = nk / 2;

  stA128(A, m0, K, 0, 0, smem, t);
  stA128(A, m0, K, 0, 1, smem, t);
  stB128(B, n0, K, 0, smem, t);
  stB128(B, n0, K, 1, smem, t);
  VM2_;
  __builtin_amdgcn_sched_barrier(0);
  __builtin_amdgcn_s_barrier();
  __builtin_amdgcn_sched_barrier(0);

  bf16x8 af[2][2];
  bf16x8 bf[4][2];

  for (int j = 0; j < nj; ++j) {
    const bool st = (j + 1 < nj);
    const int k1 = 2 * j + 1;
    PH128(0, 0, 0, 1, 1, stA128(A, m0, K, k1, 0, smem, t), );
    PH128(0, 0, 1, 0, 1, stA128(A, m0, K, k1, 1, smem, t), );
    PH128(0, 1, 0, 1, 0,
          if (st) stB128(B, n0, K, k1 + 1, smem, t), );
    PH128(0, 1, 1, 0, 0,
          if (st) stA128(A, m0, K, k1 + 1, 0, smem, t),
          { if (st) { VM4_; } else { VM0_; } });
    PH128(49152, 0, 0, 1, 1,
          if (st) stA128(A, m0, K, k1 + 1, 1, smem, t), );
    PH128(49152, 0, 1, 0, 1, , );
    PH128(49152, 1, 0, 1, 0,
          if (st) stB128(B, n0, K, k1 + 2, smem, t), );
    PH128(49152, 1, 1, 0, 0, ,
          { if (st) { VM2_; } });
  }

  float* slab = (float*)(smem + wv * 4352);
  const bool vmode = (vtb != nullptr) && ((n0 + wn * 64) >= 2 * DMODEL);
  if (vmode) {
    int vcol = n0 + wn * 64 + lane - 2 * DMODEL;
    int h = vcol >> 6, d = vcol & 63;
    int b = m0 >> 11;
    unsigned short* vdst = vtb + ((size_t)(b * NH + h) * 64 + d) * SEQ;
    float bv = bias[n0 + wn * 64 + lane];
#pragma unroll
    for (int m = 0; m < 4; ++m) {
#pragma unroll
      for (int n = 0; n < 4; ++n)
#pragma unroll
        for (int j = 0; j < 4; ++j)
          slab[(fq * 4 + j) * 68 + n * 16 + fr] = acc[m][n][j];
      int s0 = (m0 & (SEQ - 1)) + wm * 64 + m * 16;
      unsigned int pk[8];
#pragma unroll
      for (int r2 = 0; r2 < 8; ++r2)
        pk[r2] = cvtpk(slab[(2 * r2) * 68 + lane] + bv,
                       slab[(2 * r2 + 1) * 68 + lane] + bv);
      *(uint4*)(vdst + s0) = *(uint4*)&pk[0];
      *(uint4*)(vdst + s0 + 8) = *(uint4*)&pk[4];
    }
  } else {
#pragma unroll
    for (int m = 0; m < 4; ++m) {
#pragma unroll
      for (int n = 0; n < 4; ++n)
#pragma unroll
        for (int j = 0; j < 4; ++j)
          slab[(fq * 4 + j) * 68 + n * 16 + fr] = acc[m][n][j];
      int rg0 = m0 + wm * 64 + m * 16;
#pragma unroll
      for (int it = 0; it < 4; ++it) {
        int u = it * 64 + lane;
        int row = u >> 4, seg = u & 15;
        float4 v = *(const float4*)&slab[row * 68 + seg * 4];
        int col = n0 + wn * 64 + seg * 4;
        float4 b4 = *(const float4*)&bias[col];
        v.x += b4.x; v.y += b4.y; v.z += b4.z; v.w += b4.w;
        if (relu) {
          v.x = fmaxf(v.x, 0.f); v.y = fmaxf(v.y, 0.f);
          v.z = fmaxf(v.z, 0.f); v.w = fmaxf(v.w, 0.f);
        }
        size_t idx = (size_t)(rg0 + row) * N + col;
        if (resid) {
          float4 r4 = *(const float4*)&resid[idx];
          v.x += r4.x; v.y += r4.y; v.z += r4.z; v.w += r4.w;
        } else if (residb) {
          ushort4 r4 = *(const ushort4*)&residb[idx];
          v.x += bf2f(r4.x); v.y += bf2f(r4.y); v.z += bf2f(r4.z); v.w += bf2f(r4.w);
        }
        if (Cf) {
          *(float4*)&Cf[idx] = v;
        } else {
          ushort4 ob;
          ob.x = f2bf(v.x); ob.y = f2bf(v.y); ob.z = f2bf(v.z); ob.w = f2bf(v.w);
          *(ushort4*)&Cb[idx] = ob;
        }
      }
    }
  }
}

// ---------------------------------------------------------------------------
// MFMA flash attention v7: v5 math with 4-wave blocks (q-tile 128) and the
// epilogue slab aliased onto the dead K buffer -> LDS 32 KB -> 5 blocks/CU
// (20 waves/CU), smaller barrier domains. Per-wave work identical to v5;
// each wave stages 16 K-rows + 16 V-rows (2 gload16 each, same swizzle:
// (row+8)&7 == row&7).
// ---------------------------------------------------------------------------
__global__ __launch_bounds__(256, 4)
void attn_kernel(const unsigned short* __restrict__ qkv, const unsigned short* __restrict__ vtb,
                 unsigned short* __restrict__ ctxb) {
  __shared__ __align__(16) char asmem[32768];
  auto Ks  = (unsigned short(*)[64][64])(asmem);           // [2][64][64] 16KB
  auto Vts = (unsigned short(*)[64][64])(asmem + 16384);   // [2][64][64] 16KB

  const int t = threadIdx.x;
  const int lane = t & 63;
  const int wq = t >> 6;            // 0..3: q-rows [q0 + wq*32, +32)
  const int l31 = lane & 31;
  const int hi1 = lane >> 5;
  const int bid = blockIdx.x;
  const int bh = bid & 63;          // bh fastest -> same-bh blocks share XCD
  const int qt = bid >> 6;          // 0..15
  const int b = bh >> 4, h = bh & 15;
  const int q0 = qt * 128;

  const size_t RS = 3 * DMODEL;
  const unsigned short* qb = qkv + (size_t)b * SEQ * RS + h * DHEAD;
  const unsigned short* kb = qb + DMODEL;

  bf16x8 qf[4];
  {
    const unsigned short* qrow = qb + (size_t)(q0 + wq * 32 + l31) * RS;
#pragma unroll
    for (int s = 0; s < 4; ++s)
      qf[s] = *(const bf16x8*)(qrow + s * 16 + hi1 * 8);
  }

  // staging: wave wq stages rows [wq*16, wq*16+16) of K and V (2 gloads each)
  const unsigned short* kgl =
      kb + (size_t)(wq * 16 + (lane >> 3)) * RS + ((lane & 7) ^ (lane >> 3)) * 8;
  const unsigned short* vgl =
      vtb + ((size_t)bh * 64 + wq * 16 + (lane >> 3)) * SEQ + ((lane & 7) ^ (lane >> 3)) * 8;

  f32x16 oacc[2] = {};
  float lacc = 0.f;

  gload16(kgl, (char*)&Ks[0][wq * 16][0]);
  gload16(kgl + 8 * RS, (char*)&Ks[0][wq * 16 + 8][0]);
  gload16(vgl, (char*)&Vts[0][wq * 16][0]);
  gload16(vgl + 8 * SEQ, (char*)&Vts[0][wq * 16 + 8][0]);
  __syncthreads();

  const float C = 0.18033688011112042f;   // 0.125 * log2(e)

  for (int kt = 0; kt < NT; ++kt) {
    const int cur = kt & 1;
    if (kt + 1 < NT) {
      size_t ko = (size_t)(kt + 1) * 64 * RS;
      size_t vo = (size_t)(kt + 1) * 64;
      gload16(kgl + ko, (char*)&Ks[cur ^ 1][wq * 16][0]);
      gload16(kgl + ko + 8 * RS, (char*)&Ks[cur ^ 1][wq * 16 + 8][0]);
      gload16(vgl + vo, (char*)&Vts[cur ^ 1][wq * 16][0]);
      gload16(vgl + vo + 8 * SEQ, (char*)&Vts[cur ^ 1][wq * 16 + 8][0]);
    }

    f32x16 sacc[2] = {};
    __builtin_amdgcn_s_setprio(1);
#pragma unroll
    for (int s = 0; s < 4; ++s) {
#pragma unroll
      for (int kvt = 0; kvt < 2; ++kvt) {
        int row = kvt * 32 + l31;
        bf16x8 kf = *(const bf16x8*)&Ks[cur][row][(((2 * s + hi1) ^ (row & 7)) * 8)];
        sacc[kvt] = __builtin_amdgcn_mfma_f32_32x32x16_bf16(kf, qf[s], sacc[kvt], 0, 0, 0);
      }
    }
    __builtin_amdgcn_s_setprio(0);

#pragma unroll
    for (int kvt = 0; kvt < 2; ++kvt) {
      float p[16];
#pragma unroll
      for (int r = 0; r < 16; ++r) p[r] = fexp2(sacc[kvt][r] * C);
      float ps = 0.f;
#pragma unroll
      for (int r = 0; r < 16; ++r) ps += p[r];
      lacc += ps;
#pragma unroll
      for (int half = 0; half < 2; ++half) {
        const int lo = half * 8;
        unsigned int x0 = cvtpk(p[lo + 0], p[lo + 1]);
        unsigned int x1 = cvtpk(p[lo + 2], p[lo + 3]);
        unsigned int y0 = cvtpk(p[lo + 4], p[lo + 5]);
        unsigned int y1 = cvtpk(p[lo + 6], p[lo + 7]);
        plswap(x0, y0);
        plswap(x1, y1);
        bf16x8 pa = __builtin_bit_cast(bf16x8, (u32x4){x0, x1, y0, y1});
        const int s2 = kvt * 2 + half;
        __builtin_amdgcn_s_setprio(1);
#pragma unroll
        for (int dt = 0; dt < 2; ++dt) {
          int vrow = dt * 32 + l31;
          bf16x8 vf = *(const bf16x8*)&Vts[cur][vrow][(((2 * s2 + hi1) ^ (vrow & 7)) * 8)];
          oacc[dt] = __builtin_amdgcn_mfma_f32_32x32x16_bf16(pa, vf, oacc[dt], 0, 0, 0);
        }
        __builtin_amdgcn_s_setprio(0);
      }
    }
    __syncthreads();
  }

  lacc += __shfl_xor(lacc, 32);
  float inv = 1.0f / lacc;

  float iv[16];
#pragma unroll
  for (int r = 0; r < 16; ++r)
    iv[r] = __shfl(inv, (r & 3) + 8 * (r >> 2) + 4 * hi1);

  // epilogue slab aliases the dead Ks region (all loop reads completed at the
  // final barrier; slab is wave-private 4 KB at wq*2048 ushorts).
  unsigned short* slab = (unsigned short*)asmem + wq * 2048;
#pragma unroll
  for (int dt = 0; dt < 2; ++dt) {
    const int chunk = dt * 4 + (l31 >> 3);
    const int e7 = l31 & 7;
#pragma unroll
    for (int r = 0; r < 16; ++r) {
      int qp = (r & 3) + 8 * (r >> 2) + 4 * hi1;
      slab[qp * 64 + ((chunk ^ (qp & 7)) * 8) + e7] = f2bf(oacc[dt][r] * iv[r]);
    }
  }
#pragma unroll
  for (int it = 0; it < 4; ++it) {
    int u = it * 64 + lane;
    int row = u >> 3, s = u & 7;
    uint4 v = *(const uint4*)&slab[row * 64 + ((s ^ (row & 7)) * 8)];
    *(uint4*)(ctxb + (size_t)(b * SEQ + q0 + wq * 32 + row) * DMODEL + h * DHEAD + s * 8) = v;
  }
}

// ---------------------------------------------------------------------------
// LayerNorm: input f32 (Zf) or bf16 (Zb); outputs f32 (Yf) and/or bf16 (Yb).
// ---------------------------------------------------------------------------
__global__ __launch_bounds__(256)
void ln_kernel(const float* __restrict__ Zf, const unsigned short* __restrict__ Zb,
               const float* __restrict__ g, const float* __restrict__ bta,
               float* __restrict__ Yf, unsigned short* __restrict__ Yb) {
  const int row = blockIdx.x;
  float4 v;
  if (Zf) {
    v = ((const float4*)(Zf + (size_t)row * DMODEL))[threadIdx.x];
  } else {
    ushort4 u = ((const ushort4*)(Zb + (size_t)row * DMODEL))[threadIdx.x];
    v.x = bf2f(u.x); v.y = bf2f(u.y); v.z = bf2f(u.z); v.w = bf2f(u.w);
  }
  float s = v.x + v.y + v.z + v.w;
  float ss = fmaf(v.x, v.x, fmaf(v.y, v.y, fmaf(v.z, v.z, v.w * v.w)));
#pragma unroll
  for (int o = 32; o >= 1; o >>= 1) {
    s += __shfl_xor(s, o);
    ss += __shfl_xor(ss, o);
  }
  __shared__ float red[8];
  int w = threadIdx.x >> 6;
  if ((threadIdx.x & 63) == 0) { red[w] = s; red[4 + w] = ss; }
  __syncthreads();
  s = red[0] + red[1] + red[2] + red[3];
  ss = red[4] + red[5] + red[6] + red[7];
  float mu = s * (1.0f / DMODEL);
  float var = ss * (1.0f / DMODEL) - mu * mu;
  float rs = rsqrtf(var + LNEPS);
  float4 gg = ((const float4*)g)[threadIdx.x];
  float4 bb = ((const float4*)bta)[threadIdx.x];
  float4 o;
  o.x = (v.x - mu) * rs * gg.x + bb.x;
  o.y = (v.y - mu) * rs * gg.y + bb.y;
  o.z = (v.z - mu) * rs * gg.z + bb.z;
  o.w = (v.w - mu) * rs * gg.w + bb.w;
  if (Yf) ((float4*)(Yf + (size_t)row * DMODEL))[threadIdx.x] = o;
  if (Yb) {
    ushort4 ob;
    ob.x = f2bf(o.x); ob.y = f2bf(o.y); ob.z = f2bf(o.z); ob.w = f2bf(o.w);
    ((ushort4*)(Yb + (size_t)row * DMODEL))[threadIdx.x] = ob;
  }
}

// ---------------------------------------------------------------------------
extern "C" void kernel_launch(void* const* d_in, const int* in_sizes, int n_in,
                              void* d_out, int out_size, void* d_ws, size_t ws_size,
                              hipStream_t stream) {
  const int* tokens       = (const int*)d_in[0];
  const float* emb        = (const float*)d_in[1];
  const float* in_proj_w  = (const float*)d_in[2];
  const float* in_proj_b  = (const float*)d_in[3];
  const float* out_proj_w = (const float*)d_in[4];
  const float* out_proj_b = (const float*)d_in[5];
  const float* w1         = (const float*)d_in[6];
  const float* b1         = (const float*)d_in[7];
  const float* w2         = (const float*)d_in[8];
  const float* b2         = (const float*)d_in[9];
  const float* g1         = (const float*)d_in[10];
  const float* beta1      = (const float*)d_in[11];
  const float* g2         = (const float*)d_in[12];
  const float* beta2      = (const float*)d_in[13];
  float* out = (float*)d_out;

  char* ws = (char*)d_ws;
  const size_t MB = 1ull << 20;
  unsigned short* inwb   = (unsigned short*)(ws + 0 * MB);
  unsigned short* outwb  = (unsigned short*)(ws + 6 * MB);
  unsigned short* w1b    = (unsigned short*)(ws + 8 * MB);
  unsigned short* w2b    = (unsigned short*)(ws + 16 * MB);
  unsigned short* y2b    = (unsigned short*)(ws + 24 * MB);
  unsigned short* xb     = (unsigned short*)(ws + 56 * MB);
  unsigned short* qkvb   = (unsigned short*)(ws + 72 * MB);
  unsigned short* hpre_b = (unsigned short*)(ws + 72 * MB);
  unsigned short* hb     = (unsigned short*)(ws + 104 * MB);
  unsigned short* vtb    = (unsigned short*)(ws + 120 * MB);
  unsigned short* ctxb   = (unsigned short*)(ws + 136 * MB);
  unsigned short* ffbb   = (unsigned short*)(ws + 120 * MB);

  const size_t GLDSP  = 131072;   // gemm8p: 128 KB
  const size_t GLDSPN = 98304;    // gemm8p128: 96 KB

  // 1. fused embed(+posenc) -> xb and weight cvt (one launch)
  prep_kernel<<<28672, 256, 0, stream>>>(tokens, emb, xb,
                                         in_proj_w, out_proj_w, w1, w2,
                                         inwb, outwb, w1b, w2b);
  // 2. qkv = x @ in_proj_w^T + b; Q,K -> qkvb, V -> vtb (transposed epilogue)
  gemm8p128<<<(MROWS / 256) * (3 * DMODEL / 128), 512, GLDSPN, stream>>>(
      xb, inwb, in_proj_b, nullptr, nullptr, nullptr, qkvb, vtb,
      MROWS, 3 * DMODEL, DMODEL, 0);
  // 3. flash attention v7 -> ctxb (bf16)   [1024 blocks x 256 thr, 5/CU]
  attn_kernel<<<(SEQ / 128) * (BATCH * NH), 256, 0, stream>>>(qkvb, vtb, ctxb);
  // 4. hpre = ctx @ out_proj_w^T + b + xb  (bf16 out)   [256 blocks]
  gemm8p128<<<(MROWS / 256) * (DMODEL / 128), 512, GLDSPN, stream>>>(
      ctxb, outwb, out_proj_b, nullptr, xb, nullptr, hpre_b, nullptr,
      MROWS, DMODEL, DMODEL, 0);
  // 5. hb = LN1(hpre)  (bf16 in, bf16 out)
  ln_kernel<<<MROWS, 256, 0, stream>>>(nullptr, hpre_b, g1, beta1, nullptr, hb);
  // 6. ffb = relu(hb @ w1^T + b1)  (bf16 out)   [512 blocks, 8-phase 256x256]
  gemm8p<<<(MROWS / 256) * (DFF / 256), 512, GLDSP, stream>>>(
      hb, w1b, b1, nullptr, nullptr, ffbb, MROWS, DFF, DMODEL, 1);
  // 7. y2b = ffb @ w2^T + b2 + hb  (bf16 out)   [256 blocks]
  gemm8p128<<<(MROWS / 256) * (DMODEL / 128), 512, GLDSPN, stream>>>(
      ffbb, w2b, b2, nullptr, hb, nullptr, y2b, nullptr,
      MROWS, DMODEL, DFF, 0);
  // 8. out = LN2(y2b)  (bf16 in, f32 out)
  ln_kernel<<<MROWS, 256, 0, stream>>>(nullptr, y2b, g2, beta2, out, nullptr);
}

// Round 17
// 371.625 us; speedup vs baseline: 1.0471x; 1.0471x over previous
//
#include <hip/hip_runtime.h>
#include <math.h>

#define DMODEL 1024
#define NH 16
#define DHEAD 64
#define DFF 4096
#define BATCH 4
#define SEQ 2048
#define MROWS (BATCH * SEQ)   // 8192
#define LNEPS 1e-5f
#define NT (SEQ / 64)         // 32 kv tiles

typedef __attribute__((ext_vector_type(8))) short bf16x8;
typedef __attribute__((ext_vector_type(4))) float f32x4;
typedef __attribute__((ext_vector_type(16))) float f32x16;
typedef __attribute__((ext_vector_type(4))) unsigned int u32x4;

__device__ inline unsigned short f2bf(float f) {
  unsigned int u = __float_as_uint(f);
  unsigned int r = (u + 0x7fffu + ((u >> 16) & 1u)) >> 16;  // RNE
  return (unsigned short)r;
}
__device__ inline float bf2f(unsigned short b) {
  return __uint_as_float(((unsigned int)b) << 16);
}

__device__ inline void gload16(const unsigned short* g, char* l) {
  __builtin_amdgcn_global_load_lds(
      (const __attribute__((address_space(1))) unsigned int*)g,
      (__attribute__((address_space(3))) unsigned int*)l, 16, 0, 0);
}

__device__ inline float fexp2(float x) {
  float r;
  asm("v_exp_f32 %0, %1" : "=v"(r) : "v"(x));
  return r;
}
__device__ inline unsigned int cvtpk(float lo, float hi) {
  unsigned int r;
  asm("v_cvt_pk_bf16_f32 %0, %1, %2" : "=v"(r) : "v"(lo), "v"(hi));
  return r;
}
__device__ inline void plswap(unsigned int& a, unsigned int& b) {
  asm("v_permlane32_swap_b32 %0, %1" : "+v"(a), "+v"(b));
}

// QSCALE = 0.125 * log2(e): folded into Q at the qkv epilogue so attention's
// softmax is a bare exp2 of the MFMA output.
#define QSCALE 0.18033688011112042f

// ---------------------------------------------------------------------------
// Fused prologue: blocks [0,16384) do embedding+pos-enc -> bf16 xb;
// blocks [16384, 28672) do the 4-weight fp32->bf16 conversion.
// pe denom via exp2: 10000^(j/256) = 2^(j*0.051905126...), computed with one
// v_exp_f32 (error ~2^-21, far below bf16 rounding).
// ---------------------------------------------------------------------------
__global__ __launch_bounds__(256)
void prep_kernel(const int* __restrict__ tokens, const float* __restrict__ emb,
                 unsigned short* __restrict__ Xb,
                 const float* __restrict__ a, const float* __restrict__ b,
                 const float* __restrict__ c, const float* __restrict__ d,
                 unsigned short* __restrict__ oa, unsigned short* __restrict__ ob,
                 unsigned short* __restrict__ oc, unsigned short* __restrict__ od) {
  const int bid = blockIdx.x;
  if (bid < 16384) {
    const int HALF = DMODEL / 2;
    int idx = bid * 256 + threadIdx.x;
    int row = idx / HALF;
    int j = idx - row * HALF;
    int s = row & (SEQ - 1);
    int tok = tokens[row];
    float2 e = ((const float2*)(emb + (size_t)tok * DMODEL))[j];
    // 1/denom = 10000^(-j/256) = 2^(-j * log2(10000)/256)
    float inv_denom = fexp2((float)j * -0.05190512648261505f);
    float ang = (float)s * inv_denom;
    float sn, cs;
    sincosf(ang, &sn, &cs);
    ushort2 o2;
    o2.x = f2bf(e.x + sn);
    o2.y = f2bf(e.y + cs);
    ((ushort2*)(Xb + (size_t)row * DMODEL))[j] = o2;
  } else {
    int i = (bid - 16384) * 256 + threadIdx.x;
    const float* src; unsigned short* dst; int off;
    if (i < 786432)       { src = a; dst = oa; off = 0; }
    else if (i < 1048576) { src = b; dst = ob; off = 786432; }
    else if (i < 2097152) { src = c; dst = oc; off = 1048576; }
    else                  { src = d; dst = od; off = 2097152; }
    int j = i - off;
    float4 v = ((const float4*)src)[j];
    ushort4 o;
    o.x = f2bf(v.x); o.y = f2bf(v.y); o.z = f2bf(v.z); o.w = f2bf(v.w);
    ((ushort4*)dst)[j] = o;
  }
}

// ---------------------------------------------------------------------------
// gemm8p: 8-phase 256x256 GEMM (round-10 structure; ff1 only).
// ---------------------------------------------------------------------------
__device__ inline void sthalf8(const unsigned short* G, int grow0, int K, int kt,
                               char* smem_, int isB, int half, int t) {
  char* dst = smem_ + ((kt & 1) * 65536) + isB * 32768 + half * 16384;
#pragma unroll
  for (int i = 0; i < 2; ++i) {
    int g = i * 512 + t;
    int r = g >> 3, sl = g & 7;
    int c = sl ^ (r & 7);
    gload16(G + (size_t)(grow0 + half * 128 + r) * K + kt * 64 + c * 8, dst + g * 16);
  }
}

#define VM4_ asm volatile("s_waitcnt vmcnt(4)" ::: "memory")
#define VM2_ asm volatile("s_waitcnt vmcnt(2)" ::: "memory")
#define VM0_ asm volatile("s_waitcnt vmcnt(0)" ::: "memory")

#define PHASE8(bufofs, MG, NP, LA, LB, STAGE_STMT, WAIT_STMT)                   \
  {                                                                             \
    if (LA) {                                                                   \
      _Pragma("unroll") for (int m = 0; m < 4; ++m) {                           \
        int arow = wm * 128 + (MG) * 64 + m * 16 + fr;                          \
        _Pragma("unroll") for (int ks = 0; ks < 2; ++ks)                        \
          af[m][ks] = *(const bf16x8*)(smem + (bufofs) + arow * 128 +           \
                        (((ks * 4 + fq) ^ (arow & 7)) * 16));                   \
      }                                                                         \
    }                                                                           \
    if (LB) {                                                                   \
      _Pragma("unroll") for (int nn = 0; nn < 2; ++nn) {                        \
        int n = (NP) * 2 + nn;                                                  \
        int brow = wn * 64 + n * 16 + fr;                                       \
        _Pragma("unroll") for (int ks = 0; ks < 2; ++ks)                        \
          bf[(NP) * 2 + nn][ks] = *(const bf16x8*)(smem + (bufofs) + 32768 +    \
                        brow * 128 + (((ks * 4 + fq) ^ (brow & 7)) * 16));      \
      }                                                                         \
    }                                                                           \
    STAGE_STMT;                                                                 \
    __builtin_amdgcn_sched_barrier(0);                                          \
    __builtin_amdgcn_s_barrier();                                               \
    asm volatile("s_waitcnt lgkmcnt(0)" ::: "memory");                          \
    __builtin_amdgcn_sched_barrier(0);                                          \
    __builtin_amdgcn_s_setprio(1);                                              \
    _Pragma("unroll") for (int m = 0; m < 4; ++m)                               \
      _Pragma("unroll") for (int nn = 0; nn < 2; ++nn)                          \
        _Pragma("unroll") for (int ks = 0; ks < 2; ++ks)                        \
          acc[(MG) * 4 + m][(NP) * 2 + nn] =                                    \
              __builtin_amdgcn_mfma_f32_16x16x32_bf16(                          \
                  af[m][ks], bf[(NP) * 2 + nn][ks],                             \
                  acc[(MG) * 4 + m][(NP) * 2 + nn], 0, 0, 0);                   \
    __builtin_amdgcn_s_setprio(0);                                              \
    WAIT_STMT;                                                                  \
    __builtin_amdgcn_sched_barrier(0);                                          \
    __builtin_amdgcn_s_barrier();                                               \
    __builtin_amdgcn_sched_barrier(0);                                          \
  }

__global__ __launch_bounds__(512, 2)
void gemm8p(const unsigned short* __restrict__ A, const unsigned short* __restrict__ B,
            const float* __restrict__ bias, const float* __restrict__ resid,
            float* __restrict__ Cf, unsigned short* __restrict__ Cb,
            int M, int N, int K, int relu) {
  extern __shared__ char smem[];   // 131072: 2 bufs x (A 32K + B 32K)

  const int t = threadIdx.x;
  const int lane = t & 63;
  const int wv = t >> 6;
  const int wm = wv >> 2;
  const int wn = wv & 3;
  const int fr = lane & 15;
  const int fq = lane >> 4;

  const int nwg = gridDim.x;
  const int orig = blockIdx.x;
  const int q8 = nwg >> 3;
  const int wgid = (orig & 7) * q8 + (orig >> 3);
  const int stid = wgid >> 2, within = wgid & 3;
  const int sm = within & 1, sn = within >> 1;
  const int Msup = M >> 9;
  const int stm = stid % Msup, stn = stid / Msup;
  const int m0 = (stm * 2 + sm) * 256;
  const int n0 = (stn * 2 + sn) * 256;

  f32x4 acc[8][4];
#pragma unroll
  for (int m = 0; m < 8; ++m)
#pragma unroll
    for (int n = 0; n < 4; ++n) acc[m][n] = (f32x4){0.f, 0.f, 0.f, 0.f};

  const int nk = K / 64;
  const int nj = nk / 2;

  sthalf8(A, m0, K, 0, smem, 0, 0, t);
  sthalf8(A, m0, K, 0, smem, 0, 1, t);
  sthalf8(B, n0, K, 0, smem, 1, 0, t);
  sthalf8(B, n0, K, 0, smem, 1, 1, t);
  sthalf8(B, n0, K, 1, smem, 1, 0, t);
  sthalf8(B, n0, K, 1, smem, 1, 1, t);
  VM4_;
  __builtin_amdgcn_sched_barrier(0);
  __builtin_amdgcn_s_barrier();
  __builtin_amdgcn_sched_barrier(0);

  bf16x8 af[4][2];
  bf16x8 bf[4][2];

  for (int j = 0; j < nj; ++j) {
    const bool st = (j + 1 < nj);
    PHASE8(0, 0, 0, 1, 1, sthalf8(A, m0, K, 2 * j + 1, smem, 0, 0, t), );
    PHASE8(0, 0, 1, 0, 1, sthalf8(A, m0, K, 2 * j + 1, smem, 0, 1, t), );
    PHASE8(0, 1, 1, 1, 0,
           if (st) sthalf8(B, n0, K, 2 * j + 2, smem, 1, 0, t), );
    PHASE8(0, 1, 0, 0, 0,
           if (st) sthalf8(B, n0, K, 2 * j + 2, smem, 1, 1, t),
           { if (st) { VM4_; } else { VM0_; } });
    PHASE8(65536, 0, 0, 1, 1,
           if (st) sthalf8(A, m0, K, 2 * j + 2, smem, 0, 0, t), );
    PHASE8(65536, 0, 1, 0, 1,
           if (st) sthalf8(A, m0, K, 2 * j + 2, smem, 0, 1, t), );
    PHASE8(65536, 1, 1, 1, 0,
           if (st) sthalf8(B, n0, K, 2 * j + 3, smem, 1, 0, t), );
    PHASE8(65536, 1, 0, 0, 0,
           if (st) sthalf8(B, n0, K, 2 * j + 3, smem, 1, 1, t),
           { if (st) { VM4_; } });
  }

  float* slab = (float*)(smem + wv * 4352);
#pragma unroll
  for (int m = 0; m < 8; ++m) {
#pragma unroll
    for (int n = 0; n < 4; ++n)
#pragma unroll
      for (int j = 0; j < 4; ++j)
        slab[(fq * 4 + j) * 68 + n * 16 + fr] = acc[m][n][j];
    int rg0 = m0 + wm * 128 + m * 16;
#pragma unroll
    for (int it = 0; it < 4; ++it) {
      int u = it * 64 + lane;
      int row = u >> 4, seg = u & 15;
      float4 v = *(const float4*)&slab[row * 68 + seg * 4];
      int col = n0 + wn * 64 + seg * 4;
      float4 b4 = *(const float4*)&bias[col];
      v.x += b4.x; v.y += b4.y; v.z += b4.z; v.w += b4.w;
      if (relu) {
        v.x = fmaxf(v.x, 0.f); v.y = fmaxf(v.y, 0.f);
        v.z = fmaxf(v.z, 0.f); v.w = fmaxf(v.w, 0.f);
      }
      size_t idx = (size_t)(rg0 + row) * N + col;
      if (resid) {
        float4 r4 = *(const float4*)&resid[idx];
        v.x += r4.x; v.y += r4.y; v.z += r4.z; v.w += r4.w;
      }
      if (Cf) {
        *(float4*)&Cf[idx] = v;
      } else {
        ushort4 ob;
        ob.x = f2bf(v.x); ob.y = f2bf(v.y); ob.z = f2bf(v.z); ob.w = f2bf(v.w);
        *(ushort4*)&Cb[idx] = ob;
      }
    }
  }
}

// ---------------------------------------------------------------------------
// gemm8p128: fine-phase schedule at BM=256, BN=128 (qkv, out-proj, ff2).
// vtb mode (qkv only): V-region waves write their slab transposed to vtb.
// qscale mode (qkv only): Q-region waves (col < 1024) multiply by QSCALE
// before bf16 -> attention softmax is a bare exp2.
// ---------------------------------------------------------------------------
__device__ inline void stA128(const unsigned short* G, int m0, int K, int kt,
                              int half, char* smem_, int t) {
  char* dst = smem_ + ((kt & 1) * 49152) + half * 16384;
#pragma unroll
  for (int i = 0; i < 2; ++i) {
    int g = i * 512 + t;
    int r = g >> 3, sl = g & 7;
    int c = sl ^ (r & 7);
    gload16(G + (size_t)(m0 + half * 128 + r) * K + kt * 64 + c * 8, dst + g * 16);
  }
}
__device__ inline void stB128(const unsigned short* G, int n0, int K, int kt,
                              char* smem_, int t) {
  char* dst = smem_ + ((kt & 1) * 49152) + 32768;
#pragma unroll
  for (int i = 0; i < 2; ++i) {
    int g = i * 512 + t;
    int r = g >> 3, sl = g & 7;
    int c = sl ^ (r & 7);
    gload16(G + (size_t)(n0 + r) * K + kt * 64 + c * 8, dst + g * 16);
  }
}

#define PH128(bufofs, MG, NP, LA, LB, STAGE_STMT, WAIT_STMT)                    \
  {                                                                             \
    if (LA) {                                                                   \
      _Pragma("unroll") for (int mm = 0; mm < 2; ++mm) {                        \
        int arow = wm * 64 + ((MG) * 2 + mm) * 16 + fr;                         \
        _Pragma("unroll") for (int ks = 0; ks < 2; ++ks)                        \
          af[mm][ks] = *(const bf16x8*)(smem + (bufofs) + arow * 128 +          \
                        (((ks * 4 + fq) ^ (arow & 7)) * 16));                   \
      }                                                                         \
    }                                                                           \
    if (LB) {                                                                   \
      _Pragma("unroll") for (int nn = 0; nn < 2; ++nn) {                        \
        int n = (NP) * 2 + nn;                                                  \
        int brow = wn * 64 + n * 16 + fr;                                       \
        _Pragma("unroll") for (int ks = 0; ks < 2; ++ks)                        \
          bf[(NP) * 2 + nn][ks] = *(const bf16x8*)(smem + (bufofs) + 32768 +    \
                        brow * 128 + (((ks * 4 + fq) ^ (brow & 7)) * 16));      \
      }                                                                         \
    }                                                                           \
    STAGE_STMT;                                                                 \
    __builtin_amdgcn_sched_barrier(0);                                          \
    __builtin_amdgcn_s_barrier();                                               \
    asm volatile("s_waitcnt lgkmcnt(0)" ::: "memory");                          \
    __builtin_amdgcn_sched_barrier(0);                                          \
    __builtin_amdgcn_s_setprio(1);                                              \
    _Pragma("unroll") for (int mm = 0; mm < 2; ++mm)                            \
      _Pragma("unroll") for (int nn = 0; nn < 2; ++nn)                          \
        _Pragma("unroll") for (int ks = 0; ks < 2; ++ks)                        \
          acc[(MG) * 2 + mm][(NP) * 2 + nn] =                                   \
              __builtin_amdgcn_mfma_f32_16x16x32_bf16(                          \
                  af[mm][ks], bf[(NP) * 2 + nn][ks],                            \
                  acc[(MG) * 2 + mm][(NP) * 2 + nn], 0, 0, 0);                  \
    __builtin_amdgcn_s_setprio(0);                                              \
    WAIT_STMT;                                                                  \
    __builtin_amdgcn_sched_barrier(0);                                          \
    __builtin_amdgcn_s_barrier();                                               \
    __builtin_amdgcn_sched_barrier(0);                                          \
  }

__global__ __launch_bounds__(512, 2)
void gemm8p128(const unsigned short* __restrict__ A, const unsigned short* __restrict__ B,
               const float* __restrict__ bias, const float* __restrict__ resid,
               const unsigned short* __restrict__ residb,
               float* __restrict__ Cf, unsigned short* __restrict__ Cb,
               unsigned short* __restrict__ vtb, int qscale,
               int M, int N, int K, int relu) {
  extern __shared__ char smem[];   // 98304: 2 bufs x (A 32K + B 16K)

  const int t = threadIdx.x;
  const int lane = t & 63;
  const int wv = t >> 6;
  const int wm = wv >> 1;
  const int wn = wv & 1;
  const int fr = lane & 15;
  const int fq = lane >> 4;

  const int nwg = gridDim.x;
  const int orig = blockIdx.x;
  const int q8 = nwg >> 3;
  const int wgid = (orig & 7) * q8 + (orig >> 3);
  const int stid = wgid >> 2, within = wgid & 3;
  const int sm = within & 1, sn = within >> 1;
  const int Msup = M >> 9;
  const int stm = stid % Msup, stn = stid / Msup;
  const int m0 = (stm * 2 + sm) * 256;
  const int n0 = (stn * 2 + sn) * 128;

  f32x4 acc[4][4];
#pragma unroll
  for (int m = 0; m < 4; ++m)
#pragma unroll
    for (int n = 0; n < 4; ++n) acc[m][n] = (f32x4){0.f, 0.f, 0.f, 0.f};

  const int nk = K / 64;
  const int nj = nk / 2;

  stA128(A, m0, K, 0, 0, smem, t);
  stA128(A, m0, K, 0, 1, smem, t);
  stB128(B, n0, K, 0, smem, t);
  stB128(B, n0, K, 1, smem, t);
  VM2_;
  __builtin_amdgcn_sched_barrier(0);
  __builtin_amdgcn_s_barrier();
  __builtin_amdgcn_sched_barrier(0);

  bf16x8 af[2][2];
  bf16x8 bf[4][2];

  for (int j = 0; j < nj; ++j) {
    const bool st = (j + 1 < nj);
    const int k1 = 2 * j + 1;
    PH128(0, 0, 0, 1, 1, stA128(A, m0, K, k1, 0, smem, t), );
    PH128(0, 0, 1, 0, 1, stA128(A, m0, K, k1, 1, smem, t), );
    PH128(0, 1, 0, 1, 0,
          if (st) stB128(B, n0, K, k1 + 1, smem, t), );
    PH128(0, 1, 1, 0, 0,
          if (st) stA128(A, m0, K, k1 + 1, 0, smem, t),
          { if (st) { VM4_; } else { VM0_; } });
    PH128(49152, 0, 0, 1, 1,
          if (st) stA128(A, m0, K, k1 + 1, 1, smem, t), );
    PH128(49152, 0, 1, 0, 1, , );
    PH128(49152, 1, 0, 1, 0,
          if (st) stB128(B, n0, K, k1 + 2, smem, t), );
    PH128(49152, 1, 1, 0, 0, ,
          { if (st) { VM2_; } });
  }

  float* slab = (float*)(smem + wv * 4352);
  const bool vmode = (vtb != nullptr) && ((n0 + wn * 64) >= 2 * DMODEL);
  const bool qs = qscale && ((n0 + wn * 64) < DMODEL);
  if (vmode) {
    int vcol = n0 + wn * 64 + lane - 2 * DMODEL;
    int h = vcol >> 6, d = vcol & 63;
    int b = m0 >> 11;
    unsigned short* vdst = vtb + ((size_t)(b * NH + h) * 64 + d) * SEQ;
    float bv = bias[n0 + wn * 64 + lane];
#pragma unroll
    for (int m = 0; m < 4; ++m) {
#pragma unroll
      for (int n = 0; n < 4; ++n)
#pragma unroll
        for (int j = 0; j < 4; ++j)
          slab[(fq * 4 + j) * 68 + n * 16 + fr] = acc[m][n][j];
      int s0 = (m0 & (SEQ - 1)) + wm * 64 + m * 16;
      unsigned int pk[8];
#pragma unroll
      for (int r2 = 0; r2 < 8; ++r2)
        pk[r2] = cvtpk(slab[(2 * r2) * 68 + lane] + bv,
                       slab[(2 * r2 + 1) * 68 + lane] + bv);
      *(uint4*)(vdst + s0) = *(uint4*)&pk[0];
      *(uint4*)(vdst + s0 + 8) = *(uint4*)&pk[4];
    }
  } else {
#pragma unroll
    for (int m = 0; m < 4; ++m) {
#pragma unroll
      for (int n = 0; n < 4; ++n)
#pragma unroll
        for (int j = 0; j < 4; ++j)
          slab[(fq * 4 + j) * 68 + n * 16 + fr] = acc[m][n][j];
      int rg0 = m0 + wm * 64 + m * 16;
#pragma unroll
      for (int it = 0; it < 4; ++it) {
        int u = it * 64 + lane;
        int row = u >> 4, seg = u & 15;
        float4 v = *(const float4*)&slab[row * 68 + seg * 4];
        int col = n0 + wn * 64 + seg * 4;
        float4 b4 = *(const float4*)&bias[col];
        v.x += b4.x; v.y += b4.y; v.z += b4.z; v.w += b4.w;
        if (qs) {
          v.x *= QSCALE; v.y *= QSCALE; v.z *= QSCALE; v.w *= QSCALE;
        }
        if (relu) {
          v.x = fmaxf(v.x, 0.f); v.y = fmaxf(v.y, 0.f);
          v.z = fmaxf(v.z, 0.f); v.w = fmaxf(v.w, 0.f);
        }
        size_t idx = (size_t)(rg0 + row) * N + col;
        if (resid) {
          float4 r4 = *(const float4*)&resid[idx];
          v.x += r4.x; v.y += r4.y; v.z += r4.z; v.w += r4.w;
        } else if (residb) {
          ushort4 r4 = *(const ushort4*)&residb[idx];
          v.x += bf2f(r4.x); v.y += bf2f(r4.y); v.z += bf2f(r4.z); v.w += bf2f(r4.w);
        }
        if (Cf) {
          *(float4*)&Cf[idx] = v;
        } else {
          ushort4 ob;
          ob.x = f2bf(v.x); ob.y = f2bf(v.y); ob.z = f2bf(v.z); ob.w = f2bf(v.w);
          *(ushort4*)&Cb[idx] = ob;
        }
      }
    }
  }
}

// ---------------------------------------------------------------------------
// MFMA flash attention v5 (round-15 structure, best total). Q pre-scaled by
// QSCALE in the qkv epilogue -> p = exp2(sacc) directly (32 fewer v_mul per
// tile per wave on the VALU-critical path).
// ---------------------------------------------------------------------------
__global__ __launch_bounds__(512, 4)
void attn_kernel(const unsigned short* __restrict__ qkv, const unsigned short* __restrict__ vtb,
                 unsigned short* __restrict__ ctxb) {
  __shared__ __align__(16) unsigned short Ks[2][64][64];
  __shared__ __align__(16) unsigned short Vts[2][64][64];
  __shared__ __align__(16) unsigned short Slab[8][32][64];

  const int t = threadIdx.x;
  const int lane = t & 63;
  const int wq = t >> 6;
  const int l31 = lane & 31;
  const int hi1 = lane >> 5;
  const int bid = blockIdx.x;
  const int bh = bid & 63;
  const int qt = bid >> 6;
  const int b = bh >> 4, h = bh & 15;
  const int q0 = qt * 256;

  const size_t RS = 3 * DMODEL;
  const unsigned short* qb = qkv + (size_t)b * SEQ * RS + h * DHEAD;
  const unsigned short* kb = qb + DMODEL;

  bf16x8 qf[4];
  {
    const unsigned short* qrow = qb + (size_t)(q0 + wq * 32 + l31) * RS;
#pragma unroll
    for (int s = 0; s < 4; ++s)
      qf[s] = *(const bf16x8*)(qrow + s * 16 + hi1 * 8);
  }

  const unsigned short* kgl =
      kb + (size_t)(wq * 8 + (lane >> 3)) * RS + ((lane & 7) ^ (lane >> 3)) * 8;
  const unsigned short* vgl =
      vtb + ((size_t)bh * 64 + wq * 8 + (lane >> 3)) * SEQ + ((lane & 7) ^ (lane >> 3)) * 8;

  f32x16 oacc[2] = {};
  float lacc = 0.f;

  gload16(kgl, (char*)&Ks[0][wq * 8][0]);
  gload16(vgl, (char*)&Vts[0][wq * 8][0]);
  __syncthreads();

  for (int kt = 0; kt < NT; ++kt) {
    const int cur = kt & 1;
    if (kt + 1 < NT) {
      gload16(kgl + (size_t)(kt + 1) * 64 * RS, (char*)&Ks[cur ^ 1][wq * 8][0]);
      gload16(vgl + (size_t)(kt + 1) * 64, (char*)&Vts[cur ^ 1][wq * 8][0]);
    }

    f32x16 sacc[2] = {};
    __builtin_amdgcn_s_setprio(1);
#pragma unroll
    for (int s = 0; s < 4; ++s) {
#pragma unroll
      for (int kvt = 0; kvt < 2; ++kvt) {
        int row = kvt * 32 + l31;
        bf16x8 kf = *(const bf16x8*)&Ks[cur][row][(((2 * s + hi1) ^ (row & 7)) * 8)];
        sacc[kvt] = __builtin_amdgcn_mfma_f32_32x32x16_bf16(kf, qf[s], sacc[kvt], 0, 0, 0);
      }
    }
    __builtin_amdgcn_s_setprio(0);

#pragma unroll
    for (int kvt = 0; kvt < 2; ++kvt) {
      float p[16];
#pragma unroll
      for (int r = 0; r < 16; ++r) p[r] = fexp2(sacc[kvt][r]);
      float ps = 0.f;
#pragma unroll
      for (int r = 0; r < 16; ++r) ps += p[r];
      lacc += ps;
#pragma unroll
      for (int half = 0; half < 2; ++half) {
        const int lo = half * 8;
        unsigned int x0 = cvtpk(p[lo + 0], p[lo + 1]);
        unsigned int x1 = cvtpk(p[lo + 2], p[lo + 3]);
        unsigned int y0 = cvtpk(p[lo + 4], p[lo + 5]);
        unsigned int y1 = cvtpk(p[lo + 6], p[lo + 7]);
        plswap(x0, y0);
        plswap(x1, y1);
        bf16x8 pa = __builtin_bit_cast(bf16x8, (u32x4){x0, x1, y0, y1});
        const int s2 = kvt * 2 + half;
        __builtin_amdgcn_s_setprio(1);
#pragma unroll
        for (int dt = 0; dt < 2; ++dt) {
          int vrow = dt * 32 + l31;
          bf16x8 vf = *(const bf16x8*)&Vts[cur][vrow][(((2 * s2 + hi1) ^ (vrow & 7)) * 8)];
          oacc[dt] = __builtin_amdgcn_mfma_f32_32x32x16_bf16(pa, vf, oacc[dt], 0, 0, 0);
        }
        __builtin_amdgcn_s_setprio(0);
      }
    }
    __syncthreads();
  }

  lacc += __shfl_xor(lacc, 32);
  float inv = 1.0f / lacc;

  float iv[16];
#pragma unroll
  for (int r = 0; r < 16; ++r)
    iv[r] = __shfl(inv, (r & 3) + 8 * (r >> 2) + 4 * hi1);

#pragma unroll
  for (int dt = 0; dt < 2; ++dt) {
    const int chunk = dt * 4 + (l31 >> 3);
    const int e7 = l31 & 7;
#pragma unroll
    for (int r = 0; r < 16; ++r) {
      int qp = (r & 3) + 8 * (r >> 2) + 4 * hi1;
      Slab[wq][qp][((chunk ^ (qp & 7)) * 8) + e7] = f2bf(oacc[dt][r] * iv[r]);
    }
  }
#pragma unroll
  for (int it = 0; it < 4; ++it) {
    int u = it * 64 + lane;
    int row = u >> 3, s = u & 7;
    uint4 v = *(const uint4*)&Slab[wq][row][((s ^ (row & 7)) * 8)];
    *(uint4*)(ctxb + (size_t)(b * SEQ + q0 + wq * 32 + row) * DMODEL + h * DHEAD + s * 8) = v;
  }
}

// ---------------------------------------------------------------------------
// LayerNorm: input f32 (Zf) or bf16 (Zb); outputs f32 (Yf) and/or bf16 (Yb).
// ---------------------------------------------------------------------------
__global__ __launch_bounds__(256)
void ln_kernel(const float* __restrict__ Zf, const unsigned short* __restrict__ Zb,
               const float* __restrict__ g, const float* __restrict__ bta,
               float* __restrict__ Yf, unsigned short* __restrict__ Yb) {
  const int row = blockIdx.x;
  float4 v;
  if (Zf) {
    v = ((const float4*)(Zf + (size_t)row * DMODEL))[threadIdx.x];
  } else {
    ushort4 u = ((const ushort4*)(Zb + (size_t)row * DMODEL))[threadIdx.x];
    v.x = bf2f(u.x); v.y = bf2f(u.y); v.z = bf2f(u.z); v.w = bf2f(u.w);
  }
  float s = v.x + v.y + v.z + v.w;
  float ss = fmaf(v.x, v.x, fmaf(v.y, v.y, fmaf(v.z, v.z, v.w * v.w)));
#pragma unroll
  for (int o = 32; o >= 1; o >>= 1) {
    s += __shfl_xor(s, o);
    ss += __shfl_xor(ss, o);
  }
  __shared__ float red[8];
  int w = threadIdx.x >> 6;
  if ((threadIdx.x & 63) == 0) { red[w] = s; red[4 + w] = ss; }
  __syncthreads();
  s = red[0] + red[1] + red[2] + red[3];
  ss = red[4] + red[5] + red[6] + red[7];
  float mu = s * (1.0f / DMODEL);
  float var = ss * (1.0f / DMODEL) - mu * mu;
  float rs = rsqrtf(var + LNEPS);
  float4 gg = ((const float4*)g)[threadIdx.x];
  float4 bb = ((const float4*)bta)[threadIdx.x];
  float4 o;
  o.x = (v.x - mu) * rs * gg.x + bb.x;
  o.y = (v.y - mu) * rs * gg.y + bb.y;
  o.z = (v.z - mu) * rs * gg.z + bb.z;
  o.w = (v.w - mu) * rs * gg.w + bb.w;
  if (Yf) ((float4*)(Yf + (size_t)row * DMODEL))[threadIdx.x] = o;
  if (Yb) {
    ushort4 ob;
    ob.x = f2bf(o.x); ob.y = f2bf(o.y); ob.z = f2bf(o.z); ob.w = f2bf(o.w);
    ((ushort4*)(Yb + (size_t)row * DMODEL))[threadIdx.x] = ob;
  }
}

// ---------------------------------------------------------------------------
extern "C" void kernel_launch(void* const* d_in, const int* in_sizes, int n_in,
                              void* d_out, int out_size, void* d_ws, size_t ws_size,
                              hipStream_t stream) {
  const int* tokens       = (const int*)d_in[0];
  const float* emb        = (const float*)d_in[1];
  const float* in_proj_w  = (const float*)d_in[2];
  const float* in_proj_b  = (const float*)d_in[3];
  const float* out_proj_w = (const float*)d_in[4];
  const float* out_proj_b = (const float*)d_in[5];
  const float* w1         = (const float*)d_in[6];
  const float* b1         = (const float*)d_in[7];
  const float* w2         = (const float*)d_in[8];
  const float* b2         = (const float*)d_in[9];
  const float* g1         = (const float*)d_in[10];
  const float* beta1      = (const float*)d_in[11];
  const float* g2         = (const float*)d_in[12];
  const float* beta2      = (const float*)d_in[13];
  float* out = (float*)d_out;

  char* ws = (char*)d_ws;
  const size_t MB = 1ull << 20;
  unsigned short* inwb   = (unsigned short*)(ws + 0 * MB);
  unsigned short* outwb  = (unsigned short*)(ws + 6 * MB);
  unsigned short* w1b    = (unsigned short*)(ws + 8 * MB);
  unsigned short* w2b    = (unsigned short*)(ws + 16 * MB);
  unsigned short* y2b    = (unsigned short*)(ws + 24 * MB);
  unsigned short* xb     = (unsigned short*)(ws + 56 * MB);
  unsigned short* qkvb   = (unsigned short*)(ws + 72 * MB);
  unsigned short* hpre_b = (unsigned short*)(ws + 72 * MB);
  unsigned short* hb     = (unsigned short*)(ws + 104 * MB);
  unsigned short* vtb    = (unsigned short*)(ws + 120 * MB);
  unsigned short* ctxb   = (unsigned short*)(ws + 136 * MB);
  unsigned short* ffbb   = (unsigned short*)(ws + 120 * MB);

  const size_t GLDSP  = 131072;   // gemm8p: 128 KB
  const size_t GLDSPN = 98304;    // gemm8p128: 96 KB

  // 1. fused embed(+posenc) -> xb and weight cvt (one launch)
  prep_kernel<<<28672, 256, 0, stream>>>(tokens, emb, xb,
                                         in_proj_w, out_proj_w, w1, w2,
                                         inwb, outwb, w1b, w2b);
  // 2. qkv: Q(scaled),K -> qkvb, V -> vtb (transposed epilogue)
  gemm8p128<<<(MROWS / 256) * (3 * DMODEL / 128), 512, GLDSPN, stream>>>(
      xb, inwb, in_proj_b, nullptr, nullptr, nullptr, qkvb, vtb, 1,
      MROWS, 3 * DMODEL, DMODEL, 0);
  // 3. flash attention v5 -> ctxb (bf16)   [512 blocks]
  attn_kernel<<<(SEQ / 256) * (BATCH * NH), 512, 0, stream>>>(qkvb, vtb, ctxb);
  // 4. hpre = ctx @ out_proj_w^T + b + xb  (bf16 out)   [256 blocks]
  gemm8p128<<<(MROWS / 256) * (DMODEL / 128), 512, GLDSPN, stream>>>(
      ctxb, outwb, out_proj_b, nullptr, xb, nullptr, hpre_b, nullptr, 0,
      MROWS, DMODEL, DMODEL, 0);
  // 5. hb = LN1(hpre)  (bf16 in, bf16 out)
  ln_kernel<<<MROWS, 256, 0, stream>>>(nullptr, hpre_b, g1, beta1, nullptr, hb);
  // 6. ffb = relu(hb @ w1^T + b1)  (bf16 out)   [512 blocks, 8-phase 256x256]
  gemm8p<<<(MROWS / 256) * (DFF / 256), 512, GLDSP, stream>>>(
      hb, w1b, b1, nullptr, nullptr, ffbb, MROWS, DFF, DMODEL, 1);
  // 7. y2b = ffb @ w2^T + b2 + hb  (bf16 out)   [256 blocks]
  gemm8p128<<<(MROWS / 256) * (DMODEL / 128), 512, GLDSPN, stream>>>(
      ffbb, w2b, b2, nullptr, hb, nullptr, y2b, nullptr, 0,
      MROWS, DMODEL, DFF, 0);
  // 8. out = LN2(y2b)  (bf16 in, f32 out)
  ln_kernel<<<MROWS, 256, 0, stream>>>(nullptr, y2b, g2, beta2, out, nullptr);
}

// Round 18
// 361.430 us; speedup vs baseline: 1.0767x; 1.0282x over previous
//
#include <hip/hip_runtime.h>
#include <math.h>

#define DMODEL 1024
#define NH 16
#define DHEAD 64
#define DFF 4096
#define BATCH 4
#define SEQ 2048
#define MROWS (BATCH * SEQ)   // 8192
#define LNEPS 1e-5f
#define NT (SEQ / 64)         // 32 kv tiles

typedef __attribute__((ext_vector_type(8))) short bf16x8;
typedef __attribute__((ext_vector_type(4))) float f32x4;
typedef __attribute__((ext_vector_type(16))) float f32x16;
typedef __attribute__((ext_vector_type(4))) unsigned int u32x4;

__device__ inline unsigned short f2bf(float f) {
  unsigned int u = __float_as_uint(f);
  unsigned int r = (u + 0x7fffu + ((u >> 16) & 1u)) >> 16;  // RNE
  return (unsigned short)r;
}
__device__ inline float bf2f(unsigned short b) {
  return __uint_as_float(((unsigned int)b) << 16);
}

__device__ inline void gload16(const unsigned short* g, char* l) {
  __builtin_amdgcn_global_load_lds(
      (const __attribute__((address_space(1))) unsigned int*)g,
      (__attribute__((address_space(3))) unsigned int*)l, 16, 0, 0);
}

__device__ inline float fexp2(float x) {
  float r;
  asm("v_exp_f32 %0, %1" : "=v"(r) : "v"(x));
  return r;
}
__device__ inline unsigned int cvtpk(float lo, float hi) {
  unsigned int r;
  asm("v_cvt_pk_bf16_f32 %0, %1, %2" : "=v"(r) : "v"(lo), "v"(hi));
  return r;
}
__device__ inline void plswap(unsigned int& a, unsigned int& b) {
  asm("v_permlane32_swap_b32 %0, %1" : "+v"(a), "+v"(b));
}

// QSCALE = 0.125 * log2(e): folded into Q at the qkv epilogue so attention's
// softmax is a bare exp2 of the MFMA output.
#define QSCALE 0.18033688011112042f

// ---------------------------------------------------------------------------
// Fused prologue: blocks [0,16384) do embedding+pos-enc -> bf16 xb;
// blocks [16384, 28672) do the 4-weight fp32->bf16 conversion.
// ---------------------------------------------------------------------------
__global__ __launch_bounds__(256)
void prep_kernel(const int* __restrict__ tokens, const float* __restrict__ emb,
                 unsigned short* __restrict__ Xb,
                 const float* __restrict__ a, const float* __restrict__ b,
                 const float* __restrict__ c, const float* __restrict__ d,
                 unsigned short* __restrict__ oa, unsigned short* __restrict__ ob,
                 unsigned short* __restrict__ oc, unsigned short* __restrict__ od) {
  const int bid = blockIdx.x;
  if (bid < 16384) {
    const int HALF = DMODEL / 2;
    int idx = bid * 256 + threadIdx.x;
    int row = idx / HALF;
    int j = idx - row * HALF;
    int s = row & (SEQ - 1);
    int tok = tokens[row];
    float2 e = ((const float2*)(emb + (size_t)tok * DMODEL))[j];
    float inv_denom = fexp2((float)j * -0.05190512648261505f);
    float ang = (float)s * inv_denom;
    float sn, cs;
    sincosf(ang, &sn, &cs);
    ushort2 o2;
    o2.x = f2bf(e.x + sn);
    o2.y = f2bf(e.y + cs);
    ((ushort2*)(Xb + (size_t)row * DMODEL))[j] = o2;
  } else {
    int i = (bid - 16384) * 256 + threadIdx.x;
    const float* src; unsigned short* dst; int off;
    if (i < 786432)       { src = a; dst = oa; off = 0; }
    else if (i < 1048576) { src = b; dst = ob; off = 786432; }
    else if (i < 2097152) { src = c; dst = oc; off = 1048576; }
    else                  { src = d; dst = od; off = 2097152; }
    int j = i - off;
    float4 v = ((const float4*)src)[j];
    ushort4 o;
    o.x = f2bf(v.x); o.y = f2bf(v.y); o.z = f2bf(v.z); o.w = f2bf(v.w);
    ((ushort4*)dst)[j] = o;
  }
}

// ---------------------------------------------------------------------------
// gemm8p: 8-phase 256x256 GEMM (ff1 only). Supertile 4x4 (WS ~4MB = L2/XCD).
// ---------------------------------------------------------------------------
__device__ inline void sthalf8(const unsigned short* G, int grow0, int K, int kt,
                               char* smem_, int isB, int half, int t) {
  char* dst = smem_ + ((kt & 1) * 65536) + isB * 32768 + half * 16384;
#pragma unroll
  for (int i = 0; i < 2; ++i) {
    int g = i * 512 + t;
    int r = g >> 3, sl = g & 7;
    int c = sl ^ (r & 7);
    gload16(G + (size_t)(grow0 + half * 128 + r) * K + kt * 64 + c * 8, dst + g * 16);
  }
}

#define VM4_ asm volatile("s_waitcnt vmcnt(4)" ::: "memory")
#define VM2_ asm volatile("s_waitcnt vmcnt(2)" ::: "memory")
#define VM0_ asm volatile("s_waitcnt vmcnt(0)" ::: "memory")

#define PHASE8(bufofs, MG, NP, LA, LB, STAGE_STMT, WAIT_STMT)                   \
  {                                                                             \
    if (LA) {                                                                   \
      _Pragma("unroll") for (int m = 0; m < 4; ++m) {                           \
        int arow = wm * 128 + (MG) * 64 + m * 16 + fr;                          \
        _Pragma("unroll") for (int ks = 0; ks < 2; ++ks)                        \
          af[m][ks] = *(const bf16x8*)(smem + (bufofs) + arow * 128 +           \
                        (((ks * 4 + fq) ^ (arow & 7)) * 16));                   \
      }                                                                         \
    }                                                                           \
    if (LB) {                                                                   \
      _Pragma("unroll") for (int nn = 0; nn < 2; ++nn) {                        \
        int n = (NP) * 2 + nn;                                                  \
        int brow = wn * 64 + n * 16 + fr;                                       \
        _Pragma("unroll") for (int ks = 0; ks < 2; ++ks)                        \
          bf[(NP) * 2 + nn][ks] = *(const bf16x8*)(smem + (bufofs) + 32768 +    \
                        brow * 128 + (((ks * 4 + fq) ^ (brow & 7)) * 16));      \
      }                                                                         \
    }                                                                           \
    STAGE_STMT;                                                                 \
    __builtin_amdgcn_sched_barrier(0);                                          \
    __builtin_amdgcn_s_barrier();                                               \
    asm volatile("s_waitcnt lgkmcnt(0)" ::: "memory");                          \
    __builtin_amdgcn_sched_barrier(0);                                          \
    __builtin_amdgcn_s_setprio(1);                                              \
    _Pragma("unroll") for (int m = 0; m < 4; ++m)                               \
      _Pragma("unroll") for (int nn = 0; nn < 2; ++nn)                          \
        _Pragma("unroll") for (int ks = 0; ks < 2; ++ks)                        \
          acc[(MG) * 4 + m][(NP) * 2 + nn] =                                    \
              __builtin_amdgcn_mfma_f32_16x16x32_bf16(                          \
                  af[m][ks], bf[(NP) * 2 + nn][ks],                             \
                  acc[(MG) * 4 + m][(NP) * 2 + nn], 0, 0, 0);                   \
    __builtin_amdgcn_s_setprio(0);                                              \
    WAIT_STMT;                                                                  \
    __builtin_amdgcn_sched_barrier(0);                                          \
    __builtin_amdgcn_s_barrier();                                               \
    __builtin_amdgcn_sched_barrier(0);                                          \
  }

__global__ __launch_bounds__(512, 2)
void gemm8p(const unsigned short* __restrict__ A, const unsigned short* __restrict__ B,
            const float* __restrict__ bias, const float* __restrict__ resid,
            float* __restrict__ Cf, unsigned short* __restrict__ Cb,
            int M, int N, int K, int relu) {
  extern __shared__ char smem[];   // 131072: 2 bufs x (A 32K + B 32K)

  const int t = threadIdx.x;
  const int lane = t & 63;
  const int wv = t >> 6;
  const int wm = wv >> 2;
  const int wn = wv & 3;
  const int fr = lane & 15;
  const int fq = lane >> 4;

  // XCD remap + 4x4 supertile (nwg % 8 == 0; 4 | M/256 and 4 | N/256)
  const int nwg = gridDim.x;
  const int orig = blockIdx.x;
  const int q8 = nwg >> 3;
  const int wgid = (orig & 7) * q8 + (orig >> 3);
  const int stid = wgid >> 4, within = wgid & 15;
  const int sm = within & 3, sn = within >> 2;
  const int Msup = M >> 10;                  // (M/256)/4 = 8
  const int stm = stid % Msup, stn = stid / Msup;
  const int m0 = (stm * 4 + sm) * 256;
  const int n0 = (stn * 4 + sn) * 256;

  f32x4 acc[8][4];
#pragma unroll
  for (int m = 0; m < 8; ++m)
#pragma unroll
    for (int n = 0; n < 4; ++n) acc[m][n] = (f32x4){0.f, 0.f, 0.f, 0.f};

  const int nk = K / 64;
  const int nj = nk / 2;

  sthalf8(A, m0, K, 0, smem, 0, 0, t);
  sthalf8(A, m0, K, 0, smem, 0, 1, t);
  sthalf8(B, n0, K, 0, smem, 1, 0, t);
  sthalf8(B, n0, K, 0, smem, 1, 1, t);
  sthalf8(B, n0, K, 1, smem, 1, 0, t);
  sthalf8(B, n0, K, 1, smem, 1, 1, t);
  VM4_;
  __builtin_amdgcn_sched_barrier(0);
  __builtin_amdgcn_s_barrier();
  __builtin_amdgcn_sched_barrier(0);

  bf16x8 af[4][2];
  bf16x8 bf[4][2];

  for (int j = 0; j < nj; ++j) {
    const bool st = (j + 1 < nj);
    PHASE8(0, 0, 0, 1, 1, sthalf8(A, m0, K, 2 * j + 1, smem, 0, 0, t), );
    PHASE8(0, 0, 1, 0, 1, sthalf8(A, m0, K, 2 * j + 1, smem, 0, 1, t), );
    PHASE8(0, 1, 1, 1, 0,
           if (st) sthalf8(B, n0, K, 2 * j + 2, smem, 1, 0, t), );
    PHASE8(0, 1, 0, 0, 0,
           if (st) sthalf8(B, n0, K, 2 * j + 2, smem, 1, 1, t),
           { if (st) { VM4_; } else { VM0_; } });
    PHASE8(65536, 0, 0, 1, 1,
           if (st) sthalf8(A, m0, K, 2 * j + 2, smem, 0, 0, t), );
    PHASE8(65536, 0, 1, 0, 1,
           if (st) sthalf8(A, m0, K, 2 * j + 2, smem, 0, 1, t), );
    PHASE8(65536, 1, 1, 1, 0,
           if (st) sthalf8(B, n0, K, 2 * j + 3, smem, 1, 0, t), );
    PHASE8(65536, 1, 0, 0, 0,
           if (st) sthalf8(B, n0, K, 2 * j + 3, smem, 1, 1, t),
           { if (st) { VM4_; } });
  }

  float* slab = (float*)(smem + wv * 4352);
#pragma unroll
  for (int m = 0; m < 8; ++m) {
#pragma unroll
    for (int n = 0; n < 4; ++n)
#pragma unroll
      for (int j = 0; j < 4; ++j)
        slab[(fq * 4 + j) * 68 + n * 16 + fr] = acc[m][n][j];
    int rg0 = m0 + wm * 128 + m * 16;
#pragma unroll
    for (int it = 0; it < 4; ++it) {
      int u = it * 64 + lane;
      int row = u >> 4, seg = u & 15;
      float4 v = *(const float4*)&slab[row * 68 + seg * 4];
      int col = n0 + wn * 64 + seg * 4;
      float4 b4 = *(const float4*)&bias[col];
      v.x += b4.x; v.y += b4.y; v.z += b4.z; v.w += b4.w;
      if (relu) {
        v.x = fmaxf(v.x, 0.f); v.y = fmaxf(v.y, 0.f);
        v.z = fmaxf(v.z, 0.f); v.w = fmaxf(v.w, 0.f);
      }
      size_t idx = (size_t)(rg0 + row) * N + col;
      if (resid) {
        float4 r4 = *(const float4*)&resid[idx];
        v.x += r4.x; v.y += r4.y; v.z += r4.z; v.w += r4.w;
      }
      if (Cf) {
        *(float4*)&Cf[idx] = v;
      } else {
        ushort4 ob;
        ob.x = f2bf(v.x); ob.y = f2bf(v.y); ob.z = f2bf(v.z); ob.w = f2bf(v.w);
        *(ushort4*)&Cb[idx] = ob;
      }
    }
  }
}

// ---------------------------------------------------------------------------
// gemm8p128: fine-phase schedule at BM=256, BN=128 (qkv, out-proj, ff2).
// Supertile 4x4 (qkv WS 3MB <= L2). vtb/qscale modes as round 17.
// ---------------------------------------------------------------------------
__device__ inline void stA128(const unsigned short* G, int m0, int K, int kt,
                              int half, char* smem_, int t) {
  char* dst = smem_ + ((kt & 1) * 49152) + half * 16384;
#pragma unroll
  for (int i = 0; i < 2; ++i) {
    int g = i * 512 + t;
    int r = g >> 3, sl = g & 7;
    int c = sl ^ (r & 7);
    gload16(G + (size_t)(m0 + half * 128 + r) * K + kt * 64 + c * 8, dst + g * 16);
  }
}
__device__ inline void stB128(const unsigned short* G, int n0, int K, int kt,
                              char* smem_, int t) {
  char* dst = smem_ + ((kt & 1) * 49152) + 32768;
#pragma unroll
  for (int i = 0; i < 2; ++i) {
    int g = i * 512 + t;
    int r = g >> 3, sl = g & 7;
    int c = sl ^ (r & 7);
    gload16(G + (size_t)(n0 + r) * K + kt * 64 + c * 8, dst + g * 16);
  }
}

#define PH128(bufofs, MG, NP, LA, LB, STAGE_STMT, WAIT_STMT)                    \
  {                                                                             \
    if (LA) {                                                                   \
      _Pragma("unroll") for (int mm = 0; mm < 2; ++mm) {                        \
        int arow = wm * 64 + ((MG) * 2 + mm) * 16 + fr;                         \
        _Pragma("unroll") for (int ks = 0; ks < 2; ++ks)                        \
          af[mm][ks] = *(const bf16x8*)(smem + (bufofs) + arow * 128 +          \
                        (((ks * 4 + fq) ^ (arow & 7)) * 16));                   \
      }                                                                         \
    }                                                                           \
    if (LB) {                                                                   \
      _Pragma("unroll") for (int nn = 0; nn < 2; ++nn) {                        \
        int n = (NP) * 2 + nn;                                                  \
        int brow = wn * 64 + n * 16 + fr;                                      \
        _Pragma("unroll") for (int ks = 0; ks < 2; ++ks)                        \
          bf[(NP) * 2 + nn][ks] = *(const bf16x8*)(smem + (bufofs) + 32768 +    \
                        brow * 128 + (((ks * 4 + fq) ^ (brow & 7)) * 16));      \
      }                                                                         \
    }                                                                           \
    STAGE_STMT;                                                                 \
    __builtin_amdgcn_sched_barrier(0);                                          \
    __builtin_amdgcn_s_barrier();                                               \
    asm volatile("s_waitcnt lgkmcnt(0)" ::: "memory");                          \
    __builtin_amdgcn_sched_barrier(0);                                          \
    __builtin_amdgcn_s_setprio(1);                                              \
    _Pragma("unroll") for (int mm = 0; mm < 2; ++mm)                            \
      _Pragma("unroll") for (int nn = 0; nn < 2; ++nn)                          \
        _Pragma("unroll") for (int ks = 0; ks < 2; ++ks)                        \
          acc[(MG) * 2 + mm][(NP) * 2 + nn] =                                   \
              __builtin_amdgcn_mfma_f32_16x16x32_bf16(                          \
                  af[mm][ks], bf[(NP) * 2 + nn][ks],                            \
                  acc[(MG) * 2 + mm][(NP) * 2 + nn], 0, 0, 0);                  \
    __builtin_amdgcn_s_setprio(0);                                              \
    WAIT_STMT;                                                                  \
    __builtin_amdgcn_sched_barrier(0);                                          \
    __builtin_amdgcn_s_barrier();                                               \
    __builtin_amdgcn_sched_barrier(0);                                          \
  }

__global__ __launch_bounds__(512, 2)
void gemm8p128(const unsigned short* __restrict__ A, const unsigned short* __restrict__ B,
               const float* __restrict__ bias, const float* __restrict__ resid,
               const unsigned short* __restrict__ residb,
               float* __restrict__ Cf, unsigned short* __restrict__ Cb,
               unsigned short* __restrict__ vtb, int qscale,
               int M, int N, int K, int relu) {
  extern __shared__ char smem[];   // 98304: 2 bufs x (A 32K + B 16K)

  const int t = threadIdx.x;
  const int lane = t & 63;
  const int wv = t >> 6;
  const int wm = wv >> 1;
  const int wn = wv & 1;
  const int fr = lane & 15;
  const int fq = lane >> 4;

  // XCD remap + 4x4 supertile (nwg % 8 == 0; 4 | M/256 and 4 | N/128)
  const int nwg = gridDim.x;
  const int orig = blockIdx.x;
  const int q8 = nwg >> 3;
  const int wgid = (orig & 7) * q8 + (orig >> 3);
  const int stid = wgid >> 4, within = wgid & 15;
  const int sm = within & 3, sn = within >> 2;
  const int Msup = M >> 10;                  // (M/256)/4 = 8
  const int stm = stid % Msup, stn = stid / Msup;
  const int m0 = (stm * 4 + sm) * 256;
  const int n0 = (stn * 4 + sn) * 128;

  f32x4 acc[4][4];
#pragma unroll
  for (int m = 0; m < 4; ++m)
#pragma unroll
    for (int n = 0; n < 4; ++n) acc[m][n] = (f32x4){0.f, 0.f, 0.f, 0.f};

  const int nk = K / 64;
  const int nj = nk / 2;

  stA128(A, m0, K, 0, 0, smem, t);
  stA128(A, m0, K, 0, 1, smem, t);
  stB128(B, n0, K, 0, smem, t);
  stB128(B, n0, K, 1, smem, t);
  VM2_;
  __builtin_amdgcn_sched_barrier(0);
  __builtin_amdgcn_s_barrier();
  __builtin_amdgcn_sched_barrier(0);

  bf16x8 af[2][2];
  bf16x8 bf[4][2];

  for (int j = 0; j < nj; ++j) {
    const bool st = (j + 1 < nj);
    const int k1 = 2 * j + 1;
    PH128(0, 0, 0, 1, 1, stA128(A, m0, K, k1, 0, smem, t), );
    PH128(0, 0, 1, 0, 1, stA128(A, m0, K, k1, 1, smem, t), );
    PH128(0, 1, 0, 1, 0,
          if (st) stB128(B, n0, K, k1 + 1, smem, t), );
    PH128(0, 1, 1, 0, 0,
          if (st) stA128(A, m0, K, k1 + 1, 0, smem, t),
          { if (st) { VM4_; } else { VM0_; } });
    PH128(49152, 0, 0, 1, 1,
          if (st) stA128(A, m0, K, k1 + 1, 1, smem, t), );
    PH128(49152, 0, 1, 0, 1, , );
    PH128(49152, 1, 0, 1, 0,
          if (st) stB128(B, n0, K, k1 + 2, smem, t), );
    PH128(49152, 1, 1, 0, 0, ,
          { if (st) { VM2_; } });
  }

  float* slab = (float*)(smem + wv * 4352);
  const bool vmode = (vtb != nullptr) && ((n0 + wn * 64) >= 2 * DMODEL);
  const bool qs = qscale && ((n0 + wn * 64) < DMODEL);
  if (vmode) {
    int vcol = n0 + wn * 64 + lane - 2 * DMODEL;
    int h = vcol >> 6, d = vcol & 63;
    int b = m0 >> 11;
    unsigned short* vdst = vtb + ((size_t)(b * NH + h) * 64 + d) * SEQ;
    float bv = bias[n0 + wn * 64 + lane];
#pragma unroll
    for (int m = 0; m < 4; ++m) {
#pragma unroll
      for (int n = 0; n < 4; ++n)
#pragma unroll
        for (int j = 0; j < 4; ++j)
          slab[(fq * 4 + j) * 68 + n * 16 + fr] = acc[m][n][j];
      int s0 = (m0 & (SEQ - 1)) + wm * 64 + m * 16;
      unsigned int pk[8];
#pragma unroll
      for (int r2 = 0; r2 < 8; ++r2)
        pk[r2] = cvtpk(slab[(2 * r2) * 68 + lane] + bv,
                       slab[(2 * r2 + 1) * 68 + lane] + bv);
      *(uint4*)(vdst + s0) = *(uint4*)&pk[0];
      *(uint4*)(vdst + s0 + 8) = *(uint4*)&pk[4];
    }
  } else {
#pragma unroll
    for (int m = 0; m < 4; ++m) {
#pragma unroll
      for (int n = 0; n < 4; ++n)
#pragma unroll
        for (int j = 0; j < 4; ++j)
          slab[(fq * 4 + j) * 68 + n * 16 + fr] = acc[m][n][j];
      int rg0 = m0 + wm * 64 + m * 16;
#pragma unroll
      for (int it = 0; it < 4; ++it) {
        int u = it * 64 + lane;
        int row = u >> 4, seg = u & 15;
        float4 v = *(const float4*)&slab[row * 68 + seg * 4];
        int col = n0 + wn * 64 + seg * 4;
        float4 b4 = *(const float4*)&bias[col];
        v.x += b4.x; v.y += b4.y; v.z += b4.z; v.w += b4.w;
        if (qs) {
          v.x *= QSCALE; v.y *= QSCALE; v.z *= QSCALE; v.w *= QSCALE;
        }
        if (relu) {
          v.x = fmaxf(v.x, 0.f); v.y = fmaxf(v.y, 0.f);
          v.z = fmaxf(v.z, 0.f); v.w = fmaxf(v.w, 0.f);
        }
        size_t idx = (size_t)(rg0 + row) * N + col;
        if (resid) {
          float4 r4 = *(const float4*)&resid[idx];
          v.x += r4.x; v.y += r4.y; v.z += r4.z; v.w += r4.w;
        } else if (residb) {
          ushort4 r4 = *(const ushort4*)&residb[idx];
          v.x += bf2f(r4.x); v.y += bf2f(r4.y); v.z += bf2f(r4.z); v.w += bf2f(r4.w);
        }
        if (Cf) {
          *(float4*)&Cf[idx] = v;
        } else {
          ushort4 ob;
          ob.x = f2bf(v.x); ob.y = f2bf(v.y); ob.z = f2bf(v.z); ob.w = f2bf(v.w);
          *(ushort4*)&Cb[idx] = ob;
        }
      }
    }
  }
}

// ---------------------------------------------------------------------------
// MFMA flash attention v5 + qscale (round-17 structure, best total).
// ---------------------------------------------------------------------------
__global__ __launch_bounds__(512, 4)
void attn_kernel(const unsigned short* __restrict__ qkv, const unsigned short* __restrict__ vtb,
                 unsigned short* __restrict__ ctxb) {
  __shared__ __align__(16) unsigned short Ks[2][64][64];
  __shared__ __align__(16) unsigned short Vts[2][64][64];
  __shared__ __align__(16) unsigned short Slab[8][32][64];

  const int t = threadIdx.x;
  const int lane = t & 63;
  const int wq = t >> 6;
  const int l31 = lane & 31;
  const int hi1 = lane >> 5;
  const int bid = blockIdx.x;
  const int bh = bid & 63;
  const int qt = bid >> 6;
  const int b = bh >> 4, h = bh & 15;
  const int q0 = qt * 256;

  const size_t RS = 3 * DMODEL;
  const unsigned short* qb = qkv + (size_t)b * SEQ * RS + h * DHEAD;
  const unsigned short* kb = qb + DMODEL;

  bf16x8 qf[4];
  {
    const unsigned short* qrow = qb + (size_t)(q0 + wq * 32 + l31) * RS;
#pragma unroll
    for (int s = 0; s < 4; ++s)
      qf[s] = *(const bf16x8*)(qrow + s * 16 + hi1 * 8);
  }

  const unsigned short* kgl =
      kb + (size_t)(wq * 8 + (lane >> 3)) * RS + ((lane & 7) ^ (lane >> 3)) * 8;
  const unsigned short* vgl =
      vtb + ((size_t)bh * 64 + wq * 8 + (lane >> 3)) * SEQ + ((lane & 7) ^ (lane >> 3)) * 8;

  f32x16 oacc[2] = {};
  float lacc = 0.f;

  gload16(kgl, (char*)&Ks[0][wq * 8][0]);
  gload16(vgl, (char*)&Vts[0][wq * 8][0]);
  __syncthreads();

  for (int kt = 0; kt < NT; ++kt) {
    const int cur = kt & 1;
    if (kt + 1 < NT) {
      gload16(kgl + (size_t)(kt + 1) * 64 * RS, (char*)&Ks[cur ^ 1][wq * 8][0]);
      gload16(vgl + (size_t)(kt + 1) * 64, (char*)&Vts[cur ^ 1][wq * 8][0]);
    }

    f32x16 sacc[2] = {};
    __builtin_amdgcn_s_setprio(1);
#pragma unroll
    for (int s = 0; s < 4; ++s) {
#pragma unroll
      for (int kvt = 0; kvt < 2; ++kvt) {
        int row = kvt * 32 + l31;
        bf16x8 kf = *(const bf16x8*)&Ks[cur][row][(((2 * s + hi1) ^ (row & 7)) * 8)];
        sacc[kvt] = __builtin_amdgcn_mfma_f32_32x32x16_bf16(kf, qf[s], sacc[kvt], 0, 0, 0);
      }
    }
    __builtin_amdgcn_s_setprio(0);

#pragma unroll
    for (int kvt = 0; kvt < 2; ++kvt) {
      float p[16];
#pragma unroll
      for (int r = 0; r < 16; ++r) p[r] = fexp2(sacc[kvt][r]);
      float ps = 0.f;
#pragma unroll
      for (int r = 0; r < 16; ++r) ps += p[r];
      lacc += ps;
#pragma unroll
      for (int half = 0; half < 2; ++half) {
        const int lo = half * 8;
        unsigned int x0 = cvtpk(p[lo + 0], p[lo + 1]);
        unsigned int x1 = cvtpk(p[lo + 2], p[lo + 3]);
        unsigned int y0 = cvtpk(p[lo + 4], p[lo + 5]);
        unsigned int y1 = cvtpk(p[lo + 6], p[lo + 7]);
        plswap(x0, y0);
        plswap(x1, y1);
        bf16x8 pa = __builtin_bit_cast(bf16x8, (u32x4){x0, x1, y0, y1});
        const int s2 = kvt * 2 + half;
        __builtin_amdgcn_s_setprio(1);
#pragma unroll
        for (int dt = 0; dt < 2; ++dt) {
          int vrow = dt * 32 + l31;
          bf16x8 vf = *(const bf16x8*)&Vts[cur][vrow][(((2 * s2 + hi1) ^ (vrow & 7)) * 8)];
          oacc[dt] = __builtin_amdgcn_mfma_f32_32x32x16_bf16(pa, vf, oacc[dt], 0, 0, 0);
        }
        __builtin_amdgcn_s_setprio(0);
      }
    }
    __syncthreads();
  }

  lacc += __shfl_xor(lacc, 32);
  float inv = 1.0f / lacc;

  float iv[16];
#pragma unroll
  for (int r = 0; r < 16; ++r)
    iv[r] = __shfl(inv, (r & 3) + 8 * (r >> 2) + 4 * hi1);

#pragma unroll
  for (int dt = 0; dt < 2; ++dt) {
    const int chunk = dt * 4 + (l31 >> 3);
    const int e7 = l31 & 7;
#pragma unroll
    for (int r = 0; r < 16; ++r) {
      int qp = (r & 3) + 8 * (r >> 2) + 4 * hi1;
      Slab[wq][qp][((chunk ^ (qp & 7)) * 8) + e7] = f2bf(oacc[dt][r] * iv[r]);
    }
  }
#pragma unroll
  for (int it = 0; it < 4; ++it) {
    int u = it * 64 + lane;
    int row = u >> 3, s = u & 7;
    uint4 v = *(const uint4*)&Slab[wq][row][((s ^ (row & 7)) * 8)];
    *(uint4*)(ctxb + (size_t)(b * SEQ + q0 + wq * 32 + row) * DMODEL + h * DHEAD + s * 8) = v;
  }
}

// ---------------------------------------------------------------------------
// LayerNorm: input f32 (Zf) or bf16 (Zb); outputs f32 (Yf) and/or bf16 (Yb).
// ---------------------------------------------------------------------------
__global__ __launch_bounds__(256)
void ln_kernel(const float* __restrict__ Zf, const unsigned short* __restrict__ Zb,
               const float* __restrict__ g, const float* __restrict__ bta,
               float* __restrict__ Yf, unsigned short* __restrict__ Yb) {
  const int row = blockIdx.x;
  float4 v;
  if (Zf) {
    v = ((const float4*)(Zf + (size_t)row * DMODEL))[threadIdx.x];
  } else {
    ushort4 u = ((const ushort4*)(Zb + (size_t)row * DMODEL))[threadIdx.x];
    v.x = bf2f(u.x); v.y = bf2f(u.y); v.z = bf2f(u.z); v.w = bf2f(u.w);
  }
  float s = v.x + v.y + v.z + v.w;
  float ss = fmaf(v.x, v.x, fmaf(v.y, v.y, fmaf(v.z, v.z, v.w * v.w)));
#pragma unroll
  for (int o = 32; o >= 1; o >>= 1) {
    s += __shfl_xor(s, o);
    ss += __shfl_xor(ss, o);
  }
  __shared__ float red[8];
  int w = threadIdx.x >> 6;
  if ((threadIdx.x & 63) == 0) { red[w] = s; red[4 + w] = ss; }
  __syncthreads();
  s = red[0] + red[1] + red[2] + red[3];
  ss = red[4] + red[5] + red[6] + red[7];
  float mu = s * (1.0f / DMODEL);
  float var = ss * (1.0f / DMODEL) - mu * mu;
  float rs = rsqrtf(var + LNEPS);
  float4 gg = ((const float4*)g)[threadIdx.x];
  float4 bb = ((const float4*)bta)[threadIdx.x];
  float4 o;
  o.x = (v.x - mu) * rs * gg.x + bb.x;
  o.y = (v.y - mu) * rs * gg.y + bb.y;
  o.z = (v.z - mu) * rs * gg.z + bb.z;
  o.w = (v.w - mu) * rs * gg.w + bb.w;
  if (Yf) ((float4*)(Yf + (size_t)row * DMODEL))[threadIdx.x] = o;
  if (Yb) {
    ushort4 ob;
    ob.x = f2bf(o.x); ob.y = f2bf(o.y); ob.z = f2bf(o.z); ob.w = f2bf(o.w);
    ((ushort4*)(Yb + (size_t)row * DMODEL))[threadIdx.x] = ob;
  }
}

// ---------------------------------------------------------------------------
extern "C" void kernel_launch(void* const* d_in, const int* in_sizes, int n_in,
                              void* d_out, int out_size, void* d_ws, size_t ws_size,
                              hipStream_t stream) {
  const int* tokens       = (const int*)d_in[0];
  const float* emb        = (const float*)d_in[1];
  const float* in_proj_w  = (const float*)d_in[2];
  const float* in_proj_b  = (const float*)d_in[3];
  const float* out_proj_w = (const float*)d_in[4];
  const float* out_proj_b = (const float*)d_in[5];
  const float* w1         = (const float*)d_in[6];
  const float* b1         = (const float*)d_in[7];
  const float* w2         = (const float*)d_in[8];
  const float* b2         = (const float*)d_in[9];
  const float* g1         = (const float*)d_in[10];
  const float* beta1      = (const float*)d_in[11];
  const float* g2         = (const float*)d_in[12];
  const float* beta2      = (const float*)d_in[13];
  float* out = (float*)d_out;

  char* ws = (char*)d_ws;
  const size_t MB = 1ull << 20;
  unsigned short* inwb   = (unsigned short*)(ws + 0 * MB);
  unsigned short* outwb  = (unsigned short*)(ws + 6 * MB);
  unsigned short* w1b    = (unsigned short*)(ws + 8 * MB);
  unsigned short* w2b    = (unsigned short*)(ws + 16 * MB);
  unsigned short* y2b    = (unsigned short*)(ws + 24 * MB);
  unsigned short* xb     = (unsigned short*)(ws + 56 * MB);
  unsigned short* qkvb   = (unsigned short*)(ws + 72 * MB);
  unsigned short* hpre_b = (unsigned short*)(ws + 72 * MB);
  unsigned short* hb     = (unsigned short*)(ws + 104 * MB);
  unsigned short* vtb    = (unsigned short*)(ws + 120 * MB);
  unsigned short* ctxb   = (unsigned short*)(ws + 136 * MB);
  unsigned short* ffbb   = (unsigned short*)(ws + 120 * MB);

  const size_t GLDSP  = 131072;   // gemm8p: 128 KB
  const size_t GLDSPN = 98304;    // gemm8p128: 96 KB

  // 1. fused embed(+posenc) -> xb and weight cvt (one launch)
  prep_kernel<<<28672, 256, 0, stream>>>(tokens, emb, xb,
                                         in_proj_w, out_proj_w, w1, w2,
                                         inwb, outwb, w1b, w2b);
  // 2. qkv: Q(scaled),K -> qkvb, V -> vtb (transposed epilogue)
  gemm8p128<<<(MROWS / 256) * (3 * DMODEL / 128), 512, GLDSPN, stream>>>(
      xb, inwb, in_proj_b, nullptr, nullptr, nullptr, qkvb, vtb, 1,
      MROWS, 3 * DMODEL, DMODEL, 0);
  // 3. flash attention v5 -> ctxb (bf16)   [512 blocks]
  attn_kernel<<<(SEQ / 256) * (BATCH * NH), 512, 0, stream>>>(qkvb, vtb, ctxb);
  // 4. hpre = ctx @ out_proj_w^T + b + xb  (bf16 out)   [256 blocks]
  gemm8p128<<<(MROWS / 256) * (DMODEL / 128), 512, GLDSPN, stream>>>(
      ctxb, outwb, out_proj_b, nullptr, xb, nullptr, hpre_b, nullptr, 0,
      MROWS, DMODEL, DMODEL, 0);
  // 5. hb = LN1(hpre)  (bf16 in, bf16 out)
  ln_kernel<<<MROWS, 256, 0, stream>>>(nullptr, hpre_b, g1, beta1, nullptr, hb);
  // 6. ffb = relu(hb @ w1^T + b1)  (bf16 out)   [512 blocks, 8-phase 256x256]
  gemm8p<<<(MROWS / 256) * (DFF / 256), 512, GLDSP, stream>>>(
      hb, w1b, b1, nullptr, nullptr, ffbb, MROWS, DFF, DMODEL, 1);
  // 7. y2b = ffb @ w2^T + b2 + hb  (bf16 out)   [256 blocks]
  gemm8p128<<<(MROWS / 256) * (DMODEL / 128), 512, GLDSPN, stream>>>(
      ffbb, w2b, b2, nullptr, hb, nullptr, y2b, nullptr, 0,
      MROWS, DMODEL, DFF, 0);
  // 8. out = LN2(y2b)  (bf16 in, f32 out)
  ln_kernel<<<MROWS, 256, 0, stream>>>(nullptr, y2b, g2, beta2, out, nullptr);
}